// Round 7
// baseline (1456.199 us; speedup 1.0000x reference)
//
#include <hip/hip_runtime.h>
#include <hip/hip_bf16.h>
#include <math.h>

#define KG 4        // dst nodes per block in kron2 (one per wave)
#define KCHUNK 128  // edges staged in LDS per kron chunk

typedef __attribute__((ext_vector_type(8))) short bfrag;   // 8 bf16 (4 VGPRs)
typedef __attribute__((ext_vector_type(4))) float cfrag;   // 4 fp32 acc

__device__ __forceinline__ ushort f2bf(float f) {
    __hip_bfloat16 h = __float2bfloat16(f);
    return *(ushort*)&h;
}
__device__ __forceinline__ float bf2f(ushort u) {
    __hip_bfloat16 h;
    *(ushort*)&h = u;
    return __bfloat162float(h);
}

// ---------------------------------------------------------------- helpers
__device__ __forceinline__ void blockSum2(float& s1, float& s2, float* red) {
    #pragma unroll
    for (int off = 32; off > 0; off >>= 1) {
        s1 += __shfl_xor(s1, off);
        s2 += __shfl_xor(s2, off);
    }
    int lane = threadIdx.x & 63, wid = threadIdx.x >> 6;
    if (lane == 0) { red[wid] = s1; red[4 + wid] = s2; }
    __syncthreads();
    s1 = red[0] + red[1] + red[2] + red[3];
    s2 = red[4] + red[5] + red[6] + red[7];
}

// VALU-only full-wave sum: DPP row_shr 1/2/4/8 + row_bcast15/31, result via readlane(63).
__device__ __forceinline__ float dppWaveSum(float x) {
    float t;
    t = __int_as_float(__builtin_amdgcn_update_dpp(0, __float_as_int(x), 0x111, 0xf, 0xf, true)); x += t;
    t = __int_as_float(__builtin_amdgcn_update_dpp(0, __float_as_int(x), 0x112, 0xf, 0xf, true)); x += t;
    t = __int_as_float(__builtin_amdgcn_update_dpp(0, __float_as_int(x), 0x114, 0xf, 0xf, true)); x += t;
    t = __int_as_float(__builtin_amdgcn_update_dpp(0, __float_as_int(x), 0x118, 0xf, 0xf, true)); x += t;
    t = __int_as_float(__builtin_amdgcn_update_dpp(0, __float_as_int(x), 0x142, 0xf, 0xf, true)); x += t;
    t = __int_as_float(__builtin_amdgcn_update_dpp(0, __float_as_int(x), 0x143, 0xf, 0xf, true)); x += t;
    return __int_as_float(__builtin_amdgcn_readlane(__float_as_int(x), 63));
}

__device__ __forceinline__ float sigmoidf(float x) { return 1.0f / (1.0f + expf(-x)); }

// ---------------------------------------------------------------- bf16 cast
__global__ __launch_bounds__(256) void cast_bf16_kernel(
    const float* __restrict__ x, ushort* __restrict__ y, int n)
{
    int i = (blockIdx.x * 256 + threadIdx.x) * 4;
    if (i < n) {
        float4 v = *(const float4*)(x + i);
        ushort4 o;
        o.x = f2bf(v.x); o.y = f2bf(v.y); o.z = f2bf(v.z); o.w = f2bf(v.w);
        *(ushort4*)(y + i) = o;
    }
}

// ---------------------------------------------------------------- weight prep (bf16 B^T layouts)
__global__ __launch_bounds__(256) void prep_w_kernel(
    const float* __restrict__ Wn, const float* __restrict__ Wih,
    const float* __restrict__ Whh, const float* __restrict__ Wc,
    const float* __restrict__ b_ih, const float* __restrict__ b_hh,
    const float* __restrict__ Wp, const float* __restrict__ bp,
    const float* __restrict__ Wk,
    ushort* __restrict__ BTn, ushort* __restrict__ BTrz,
    ushort* __restrict__ BTin, ushort* __restrict__ BThn,
    ushort* __restrict__ BTc, float* __restrict__ bias_rz,
    ushort* __restrict__ BTp, float* __restrict__ bp_pad,
    ushort* __restrict__ W2t)
{
    int id = blockIdx.x * 256 + threadIdx.x;
    if (id < 262144) {
        int n = id >> 9, k = id & 511;
        float v = (k < 256) ? Wih[n * 256 + k] : Whh[n * 256 + k - 256];
        BTrz[id] = f2bf(v);
    } else if (id < 327680) {
        int j = id - 262144; int n = j >> 8, k = j & 255;
        BTin[j] = f2bf(Wih[(512 + n) * 256 + k]);
    } else if (id < 393216) {
        int j = id - 327680; int n = j >> 8, k = j & 255;
        BThn[j] = f2bf(Whh[(512 + n) * 256 + k]);
    } else if (id < 458752) {
        int j = id - 393216; int n = j >> 8, k = j & 255;
        BTn[j] = f2bf(Wn[k * 256 + n]);
    } else if (id < 589824) {
        int j = id - 458752; int n = j >> 9, k = j & 511;
        BTc[j] = f2bf(Wc[k * 256 + n]);
    } else if (id < 590336) {
        int n = id - 589824;
        bias_rz[n] = b_ih[n] + b_hh[n];
    } else if (id < 623104) {
        int j = id - 590336; int n = j >> 8, k = j & 255;
        BTp[j] = f2bf((n < 20) ? Wp[k * 20 + n] : 0.f);
    } else if (id < 623232) {
        int n = id - 623104;
        bp_pad[n] = (n < 20) ? bp[n] : 0.f;
    } else if (id < 950912) {
        // W2t[n][k] = Wk[(a*20+k)*256 + o], n = a*256+o, K padded 20->64 with zeros
        int j = id - 623232;
        int n = j >> 6, k = j & 63;
        int a = n >> 8, o = n & 255;
        W2t[j] = f2bf((k < 20) ? Wk[(size_t)(a * 20 + k) * 256 + o] : 0.f);
    }
}

// ---------------------------------------------------------------- generic bf16 MFMA GEMM (128x128, BK=64)
__global__ __launch_bounds__(256) void mfma_gemm_kernel(
    const ushort* __restrict__ A1, const ushort* __restrict__ A2, int ksplit, int lda,
    const ushort* __restrict__ B, const float* __restrict__ bias,
    void* __restrict__ Cout, int store_bf16,
    int M, int N, int K, int ldc)
{
    __shared__ ushort As[128 * 64];
    __shared__ ushort Bs[128 * 64];
    int t = threadIdx.x;
    int m0 = blockIdx.x * 128, n0 = blockIdx.y * 128;
    int w = t >> 6, lane = t & 63;
    int q = lane >> 4, r = lane & 15;
    int wm = (w & 1) * 64, wn = (w >> 1) * 64;

    cfrag acc[4][4] = {};

    int srow_base = t >> 3;
    int skc = t & 7;

    for (int k0 = 0; k0 < K; k0 += 64) {
        const ushort* Ap; int kb;
        if (k0 < ksplit) { Ap = A1; kb = k0; } else { Ap = A2; kb = k0 - ksplit; }
        int4 av[4], bv[4];
        #pragma unroll
        for (int i = 0; i < 4; ++i) {
            int row = i * 32 + srow_base;
            int grow = m0 + row;
            av[i] = make_int4(0, 0, 0, 0);
            if (grow < M) av[i] = *(const int4*)(Ap + (size_t)grow * lda + kb + skc * 8);
            bv[i] = *(const int4*)(B + (size_t)(n0 + row) * K + k0 + skc * 8);
        }
        __syncthreads();
        #pragma unroll
        for (int i = 0; i < 4; ++i) {
            int row = i * 32 + srow_base;
            int off = row * 64 + ((skc ^ (row & 7)) * 8);
            *(int4*)&As[off] = av[i];
            *(int4*)&Bs[off] = bv[i];
        }
        __syncthreads();
        #pragma unroll
        for (int s = 0; s < 2; ++s) {
            bfrag af[4], bfr[4];
            int kc = s * 4 + q;
            #pragma unroll
            for (int mi = 0; mi < 4; ++mi) {
                int arow = wm + mi * 16 + r;
                af[mi] = *(const bfrag*)&As[arow * 64 + ((kc ^ (arow & 7)) * 8)];
            }
            #pragma unroll
            for (int ni = 0; ni < 4; ++ni) {
                int brow = wn + ni * 16 + r;
                bfr[ni] = *(const bfrag*)&Bs[brow * 64 + ((kc ^ (brow & 7)) * 8)];
            }
            #pragma unroll
            for (int mi = 0; mi < 4; ++mi)
                #pragma unroll
                for (int ni = 0; ni < 4; ++ni)
                    acc[mi][ni] = __builtin_amdgcn_mfma_f32_16x16x32_bf16(
                        af[mi], bfr[ni], acc[mi][ni], 0, 0, 0);
        }
    }

    float bvld[4];
    #pragma unroll
    for (int ni = 0; ni < 4; ++ni) bvld[ni] = bias[n0 + wn + ni * 16 + r];
    #pragma unroll
    for (int mi = 0; mi < 4; ++mi) {
        #pragma unroll
        for (int v = 0; v < 4; ++v) {
            int grow = m0 + wm + mi * 16 + q * 4 + v;
            if (grow >= M) continue;
            #pragma unroll
            for (int ni = 0; ni < 4; ++ni) {
                int gcol = n0 + wn + ni * 16 + r;
                if (gcol >= N) continue;
                float val = acc[mi][ni][v] + bvld[ni];
                if (store_bf16) ((ushort*)Cout)[(size_t)grow * ldc + gcol] = f2bf(val);
                else            ((float*)Cout)[(size_t)grow * ldc + gcol] = val;
            }
        }
    }
}

// ---------------------------------------------------------------- LN(20)+relu on npj32 [V,32] -> npj [V,20] + npj64 bf16 [V,64]
__global__ __launch_bounds__(256) void ln20_kernel(
    const float* __restrict__ npj32, const float* __restrict__ gp,
    const float* __restrict__ betap, float* __restrict__ npj,
    ushort* __restrict__ npj64, int V)
{
    int wid = threadIdx.x >> 6, j = threadIdx.x & 63;
    int v = blockIdx.x * 4 + wid;
    if (v >= V) return;
    float acc = (j < 20) ? npj32[(size_t)v * 32 + j] : 0.f;
    float s1 = acc, s2 = acc * acc;
    #pragma unroll
    for (int off = 32; off > 0; off >>= 1) {
        s1 += __shfl_xor(s1, off);
        s2 += __shfl_xor(s2, off);
    }
    float mu = s1 * (1.0f / 20.0f);
    float var = s2 * (1.0f / 20.0f) - mu * mu;
    float yr = 0.f;
    if (j < 20) {
        float y = (acc - mu) * rsqrtf(var + 1e-5f) * gp[j] + betap[j];
        yr = fmaxf(y, 0.f);
        npj[(size_t)v * 20 + j] = yr;
    }
    npj64[(size_t)v * 64 + j] = f2bf(yr);
}

// ---------------------------------------------------------------- CSR build
__global__ __launch_bounds__(256) void deg_kernel(const int* __restrict__ dst, int* __restrict__ deg, int E) {
    int e = blockIdx.x * 256 + threadIdx.x;
    if (e < E) atomicAdd(&deg[dst[e]], 1);
}

__global__ __launch_bounds__(1024) void scan_kernel(const int* __restrict__ deg, int* __restrict__ row, int V) {
    __shared__ int wsum[16];
    __shared__ int carry_sh;
    int t = threadIdx.x, lane = t & 63, wid = t >> 6;
    if (t == 0) carry_sh = 0;
    __syncthreads();
    for (int base = 0; base < V; base += 1024) {
        int i = base + t;
        int val = (i < V) ? deg[i] : 0;
        #pragma unroll
        for (int s = 1; s < 64; s <<= 1) {
            int n = __shfl_up(val, s);
            if (lane >= s) val += n;
        }
        if (lane == 63) wsum[wid] = val;
        __syncthreads();
        if (wid == 0) {
            int x = (lane < 16) ? wsum[lane] : 0;
            #pragma unroll
            for (int s = 1; s < 16; s <<= 1) {
                int n = __shfl_up(x, s);
                if (lane >= s) x += n;
            }
            if (lane < 16) wsum[lane] = x;
        }
        __syncthreads();
        int wprefix = (wid > 0) ? wsum[wid - 1] : 0;
        int c = carry_sh;
        int incl = c + wprefix + val;
        if (i < V) row[i + 1] = incl;
        __syncthreads();
        if (t == 1023) carry_sh = incl;
    }
    if (t == 0) row[0] = 0;
}

__global__ __launch_bounds__(256) void scatter_kernel(
    const int* __restrict__ dst, const int* __restrict__ row,
    int* __restrict__ cnt, int* __restrict__ eorder, int E)
{
    int e = blockIdx.x * 256 + threadIdx.x;
    if (e < E) {
        int d = dst[e];
        int pos = row[d] + atomicAdd(&cnt[d], 1);
        eorder[pos] = e;
    }
}

// ---------------------------------------------------------------- per-node edge-logit projections
__global__ __launch_bounds__(256) void nodeproj_kernel(
    const float* __restrict__ nf, const float* __restrict__ We,
    float* __restrict__ pd, float* __restrict__ ps, int V)
{
    int wid = threadIdx.x >> 6, lane = threadIdx.x & 63;
    int v = blockIdx.x * 4 + wid;
    if (v >= V) return;
    const float* row = nf + (size_t)v * 256;
    int i = lane * 4;
    float4 x  = *(const float4*)(row + i);
    float4 wd = *(const float4*)(We + i);
    float4 wsv = *(const float4*)(We + 256 + i);
    float sd = x.x * wd.x + x.y * wd.y + x.z * wd.z + x.w * wd.w;
    float ss = x.x * wsv.x + x.y * wsv.y + x.z * wsv.z + x.w * wsv.w;
    #pragma unroll
    for (int off = 32; off > 0; off >>= 1) {
        sd += __shfl_xor(sd, off);
        ss += __shfl_xor(ss, off);
    }
    if (lane == 0) { pd[v] = sd; ps[v] = ss; }
}

// ---------------------------------------------------------------- edge prep (eorder order)
__global__ __launch_bounds__(256) void edgeprep_kernel(
    const int* __restrict__ eorder, const int* __restrict__ src, const int* __restrict__ dst,
    const float* __restrict__ pd, const float* __restrict__ ps, const float* __restrict__ be,
    float* __restrict__ logitOrd, int* __restrict__ srcOrd, int E)
{
    int p = blockIdx.x * 256 + threadIdx.x;
    if (p < E) {
        int e = eorder[p];
        int s = src[e], d = dst[e];
        srcOrd[p] = s;
        logitOrd[p] = fmaxf(pd[d] + ps[s] + be[0], 0.f);
    }
}

// ---------------------------------------------------------------- kron stage-2 using materialized T
// Tr from global T_bf[v - vlo][a*256 + c] (coalesced ushort4); rest identical to the proven
// stage-2: chunked sE LDS staging, float4 reads, DPP LN reductions, per-wave dst accumulate.
// LDS only 10 KB -> ~4 blocks/CU occupancy (vs 1.6 for the fused version).
__global__ __launch_bounds__(256) void kron2_kernel(
    const float* __restrict__ npj, const int* __restrict__ srcOrd,
    const int* __restrict__ rowPtr, const ushort* __restrict__ Tb,
    const float* __restrict__ bk, const float* __restrict__ gkv,
    const float* __restrict__ betak, ushort* __restrict__ acat,
    int vlo, int vhi)
{
    __shared__ float sE[KCHUNK * 20];             // 10 KB
    int t = threadIdx.x;
    int v0 = vlo + blockIdx.x * KG;
    int wid = t >> 6, lane = t & 63;
    int v = v0 + wid;
    int c0 = lane * 4;

    float Tr[20][4];
    if (v < vhi) {
        const ushort* trow = Tb + (size_t)(v - vlo) * 5120;
        #pragma unroll
        for (int a = 0; a < 20; ++a) {
            ushort4 u = *(const ushort4*)(trow + a * 256 + c0);
            Tr[a][0] = bf2f(u.x); Tr[a][1] = bf2f(u.y);
            Tr[a][2] = bf2f(u.z); Tr[a][3] = bf2f(u.w);
        }
    } else {
        #pragma unroll
        for (int a = 0; a < 20; ++a) {
            Tr[a][0] = 0.f; Tr[a][1] = 0.f; Tr[a][2] = 0.f; Tr[a][3] = 0.f;
        }
    }
    float4 bkv = *(const float4*)(bk + c0);
    float4 gk4 = *(const float4*)(gkv + c0);
    float4 bt4 = *(const float4*)(betak + c0);

    int eBase = rowPtr[v0];
    int vEnd = (v0 + KG < vhi) ? (v0 + KG) : vhi;
    int eEndB = rowPtr[vEnd];
    int myE0 = (v < vhi) ? rowPtr[v] : 0;
    int myE1 = (v < vhi) ? rowPtr[v + 1] : 0;

    float a0 = 0.f, a1 = 0.f, a2 = 0.f, a3 = 0.f;

    for (int base = eBase; base < eEndB; base += KCHUNK) {
        int nC = eEndB - base; if (nC > KCHUNK) nC = KCHUNK;
        __syncthreads();   // previous chunk fully consumed
        for (int idx = t; idx < nC * 20; idx += 256) {
            int le = idx / 20, aa = idx - le * 20;
            sE[idx] = npj[(size_t)srcOrd[base + le] * 20 + aa];
        }
        __syncthreads();

        int lo = (myE0 > base) ? myE0 : base;
        int hi = (myE1 < base + nC) ? myE1 : base + nC;
        int p = lo;
        for (; p + 1 < hi; p += 2) {
            const float* sa = &sE[(p - base) * 20];
            const float* sb = &sE[(p + 1 - base) * 20];
            float4 sa0 = *(const float4*)(sa);
            float4 sa1 = *(const float4*)(sa + 4);
            float4 sa2 = *(const float4*)(sa + 8);
            float4 sa3 = *(const float4*)(sa + 12);
            float4 sa4 = *(const float4*)(sa + 16);
            float4 sb0 = *(const float4*)(sb);
            float4 sb1 = *(const float4*)(sb + 4);
            float4 sb2 = *(const float4*)(sb + 8);
            float4 sb3 = *(const float4*)(sb + 12);
            float4 sb4 = *(const float4*)(sb + 16);
            float sav[20] = {sa0.x, sa0.y, sa0.z, sa0.w, sa1.x, sa1.y, sa1.z, sa1.w,
                             sa2.x, sa2.y, sa2.z, sa2.w, sa3.x, sa3.y, sa3.z, sa3.w,
                             sa4.x, sa4.y, sa4.z, sa4.w};
            float sbv[20] = {sb0.x, sb0.y, sb0.z, sb0.w, sb1.x, sb1.y, sb1.z, sb1.w,
                             sb2.x, sb2.y, sb2.z, sb2.w, sb3.x, sb3.y, sb3.z, sb3.w,
                             sb4.x, sb4.y, sb4.z, sb4.w};
            float ya0 = bkv.x, ya1 = bkv.y, ya2 = bkv.z, ya3 = bkv.w;
            float yb0 = bkv.x, yb1 = bkv.y, yb2 = bkv.z, yb3 = bkv.w;
            #pragma unroll
            for (int a = 0; a < 20; ++a) {
                float va = sav[a], vb = sbv[a];
                ya0 += va * Tr[a][0]; ya1 += va * Tr[a][1];
                ya2 += va * Tr[a][2]; ya3 += va * Tr[a][3];
                yb0 += vb * Tr[a][0]; yb1 += vb * Tr[a][1];
                yb2 += vb * Tr[a][2]; yb3 += vb * Tr[a][3];
            }
            float s1a = dppWaveSum(ya0 + ya1 + ya2 + ya3);
            float s2a = dppWaveSum(ya0 * ya0 + ya1 * ya1 + ya2 * ya2 + ya3 * ya3);
            float s1b = dppWaveSum(yb0 + yb1 + yb2 + yb3);
            float s2b = dppWaveSum(yb0 * yb0 + yb1 * yb1 + yb2 * yb2 + yb3 * yb3);
            float mua = s1a * (1.0f / 256.0f);
            float rsa = rsqrtf(s2a * (1.0f / 256.0f) - mua * mua + 1e-5f);
            float mub = s1b * (1.0f / 256.0f);
            float rsb = rsqrtf(s2b * (1.0f / 256.0f) - mub * mub + 1e-5f);
            a0 += fmaxf((ya0 - mua) * rsa * gk4.x + bt4.x, 0.f) + fmaxf((yb0 - mub) * rsb * gk4.x + bt4.x, 0.f);
            a1 += fmaxf((ya1 - mua) * rsa * gk4.y + bt4.y, 0.f) + fmaxf((yb1 - mub) * rsb * gk4.y + bt4.y, 0.f);
            a2 += fmaxf((ya2 - mua) * rsa * gk4.z + bt4.z, 0.f) + fmaxf((yb2 - mub) * rsb * gk4.z + bt4.z, 0.f);
            a3 += fmaxf((ya3 - mua) * rsa * gk4.w + bt4.w, 0.f) + fmaxf((yb3 - mub) * rsb * gk4.w + bt4.w, 0.f);
        }
        if (p < hi) {
            const float* sa = &sE[(p - base) * 20];
            float4 sa0 = *(const float4*)(sa);
            float4 sa1 = *(const float4*)(sa + 4);
            float4 sa2 = *(const float4*)(sa + 8);
            float4 sa3 = *(const float4*)(sa + 12);
            float4 sa4 = *(const float4*)(sa + 16);
            float sav[20] = {sa0.x, sa0.y, sa0.z, sa0.w, sa1.x, sa1.y, sa1.z, sa1.w,
                             sa2.x, sa2.y, sa2.z, sa2.w, sa3.x, sa3.y, sa3.z, sa3.w,
                             sa4.x, sa4.y, sa4.z, sa4.w};
            float ya0 = bkv.x, ya1 = bkv.y, ya2 = bkv.z, ya3 = bkv.w;
            #pragma unroll
            for (int a = 0; a < 20; ++a) {
                float va = sav[a];
                ya0 += va * Tr[a][0]; ya1 += va * Tr[a][1];
                ya2 += va * Tr[a][2]; ya3 += va * Tr[a][3];
            }
            float s1a = dppWaveSum(ya0 + ya1 + ya2 + ya3);
            float s2a = dppWaveSum(ya0 * ya0 + ya1 * ya1 + ya2 * ya2 + ya3 * ya3);
            float mua = s1a * (1.0f / 256.0f);
            float rsa = rsqrtf(s2a * (1.0f / 256.0f) - mua * mua + 1e-5f);
            a0 += fmaxf((ya0 - mua) * rsa * gk4.x + bt4.x, 0.f);
            a1 += fmaxf((ya1 - mua) * rsa * gk4.y + bt4.y, 0.f);
            a2 += fmaxf((ya2 - mua) * rsa * gk4.z + bt4.z, 0.f);
            a3 += fmaxf((ya3 - mua) * rsa * gk4.w + bt4.w, 0.f);
        }
    }
    if (v < vhi) {
        ushort4 o;
        o.x = f2bf(a0); o.y = f2bf(a1); o.z = f2bf(a2); o.w = f2bf(a3);
        *(ushort4*)(acat + (size_t)v * 512 + 256 + c0) = o;
    }
}

// ---------------------------------------------------------------- attention stats per dst (linear reads)
__global__ __launch_bounds__(256) void att_kernel(
    const float* __restrict__ logitOrd, const int* __restrict__ rowPtr,
    float* __restrict__ mArr, float* __restrict__ invArr, int V)
{
    int wid = threadIdx.x >> 6, lane = threadIdx.x & 63;
    int v = blockIdx.x * 4 + wid;
    if (v >= V) return;
    int e0 = rowPtr[v], e1 = rowPtr[v + 1];
    float m = -1e30f;
    for (int p = e0 + lane; p < e1; p += 64) m = fmaxf(m, logitOrd[p]);
    #pragma unroll
    for (int off = 32; off > 0; off >>= 1) m = fmaxf(m, __shfl_xor(m, off));
    float d = 0.f;
    for (int p = e0 + lane; p < e1; p += 64) d += expf(logitOrd[p] - m);
    #pragma unroll
    for (int off = 32; off > 0; off >>= 1) d += __shfl_xor(d, off);
    if (lane == 0) {
        mArr[v] = m;
        invArr[v] = (e1 > e0) ? (1.0f / d) : 0.f;
    }
}

// ---------------------------------------------------------------- weighted context (bf16 hv, unroll x4)
__global__ __launch_bounds__(256) void ctx_kernel(
    const ushort* __restrict__ hv_bf, const float* __restrict__ logitOrd,
    const float* __restrict__ mArr, const float* __restrict__ invArr,
    const int* __restrict__ srcOrd, const int* __restrict__ rowPtr,
    ushort* __restrict__ ctx_bf, int V)
{
    int v = blockIdx.x;
    int t = threadIdx.x;
    int e0 = rowPtr[v], e1 = rowPtr[v + 1];
    float m = mArr[v], inv = invArr[v];
    float acc = 0.f;
    int p = e0;
    for (; p + 3 < e1; p += 4) {
        int s0 = srcOrd[p], s1 = srcOrd[p + 1], s2 = srcOrd[p + 2], s3 = srcOrd[p + 3];
        float w0 = expf(logitOrd[p] - m) * inv;
        float w1 = expf(logitOrd[p + 1] - m) * inv;
        float w2 = expf(logitOrd[p + 2] - m) * inv;
        float w3 = expf(logitOrd[p + 3] - m) * inv;
        float h0 = bf2f(hv_bf[(size_t)s0 * 256 + t]);
        float h1 = bf2f(hv_bf[(size_t)s1 * 256 + t]);
        float h2 = bf2f(hv_bf[(size_t)s2 * 256 + t]);
        float h3 = bf2f(hv_bf[(size_t)s3 * 256 + t]);
        acc += w0 * h0 + w1 * h1 + w2 * h2 + w3 * h3;
    }
    for (; p < e1; ++p) {
        float wgt = expf(logitOrd[p] - m) * inv;
        acc += wgt * bf2f(hv_bf[(size_t)srcOrd[p] * 256 + t]);
    }
    ctx_bf[(size_t)v * 256 + t] = f2bf(fmaxf(acc, 0.f));
}

// ---------------------------------------------------------------- GRU gates + LN -> bf16 into acat[:,0:256]
__global__ __launch_bounds__(256) void gru_ln_kernel(
    const ushort* __restrict__ rz, const ushort* __restrict__ inb,
    const ushort* __restrict__ hnb, const float* __restrict__ nf,
    const float* __restrict__ g_ln, const float* __restrict__ b_ln,
    ushort* __restrict__ acat, int V)
{
    __shared__ float red[8];
    int v = blockIdx.x, t = threadIdx.x;
    float r = sigmoidf(bf2f(rz[(size_t)v * 512 + t]));
    float z = sigmoidf(bf2f(rz[(size_t)v * 512 + 256 + t]));
    float n = tanhf(bf2f(inb[(size_t)v * 256 + t]) + r * bf2f(hnb[(size_t)v * 256 + t]));
    float h = (1.f - z) * n + z * nf[(size_t)v * 256 + t];
    float x = fmaxf(h, 0.f);
    float s1 = x, s2 = x * x;
    blockSum2(s1, s2, red);
    float mu = s1 * (1.0f / 256.0f);
    float var = s2 * (1.0f / 256.0f) - mu * mu;
    float y = (x - mu) * rsqrtf(var + 1e-5f) * g_ln[t] + b_ln[t];
    acat[(size_t)v * 512 + t] = f2bf(y);
}

// ---------------------------------------------------------------- row LayerNorm (optional relu)
__global__ __launch_bounds__(256) void ln_kernel(
    const float* __restrict__ in, float* __restrict__ out,
    const float* __restrict__ g, const float* __restrict__ b, int relu_after)
{
    __shared__ float red[8];
    int v = blockIdx.x, t = threadIdx.x;
    float x = in[(size_t)v * 256 + t];
    float s1 = x, s2 = x * x;
    blockSum2(s1, s2, red);
    float mu = s1 * (1.0f / 256.0f);
    float var = s2 * (1.0f / 256.0f) - mu * mu;
    float y = (x - mu) * rsqrtf(var + 1e-5f) * g[t] + b[t];
    if (relu_after) y = fmaxf(y, 0.f);
    out[(size_t)v * 256 + t] = y;
}

// ---------------------------------------------------------------- launcher
extern "C" void kernel_launch(void* const* d_in, const int* in_sizes, int n_in,
                              void* d_out, int out_size, void* d_ws, size_t ws_size,
                              hipStream_t stream)
{
    const float* nf    = (const float*)d_in[0];
    const int*   src   = (const int*)d_in[1];
    const int*   dst   = (const int*)d_in[2];
    const float* Wp    = (const float*)d_in[3];
    const float* bp    = (const float*)d_in[4];
    const float* gp    = (const float*)d_in[5];
    const float* betap = (const float*)d_in[6];
    const float* Wk    = (const float*)d_in[7];
    const float* bk    = (const float*)d_in[8];
    const float* gk    = (const float*)d_in[9];
    const float* betak = (const float*)d_in[10];
    const float* We    = (const float*)d_in[11];
    const float* be    = (const float*)d_in[12];
    const float* Wn    = (const float*)d_in[13];
    const float* bn    = (const float*)d_in[14];
    const float* W_ih  = (const float*)d_in[15];
    const float* W_hh  = (const float*)d_in[16];
    const float* b_ih  = (const float*)d_in[17];
    const float* b_hh  = (const float*)d_in[18];
    const float* g_ln  = (const float*)d_in[19];
    const float* bt_ln = (const float*)d_in[20];
    const float* Wc    = (const float*)d_in[21];
    const float* bc    = (const float*)d_in[22];
    const float* gc    = (const float*)d_in[23];
    const float* betac = (const float*)d_in[24];

    int V = in_sizes[0] / 256;
    int E = in_sizes[1];

    char* w = (char*)d_ws;
    auto alloc = [&](size_t bytes) -> char* {
        char* p = w;
        w += (bytes + 255) & ~(size_t)255;
        return p;
    };
    float*  npj      = (float*)alloc((size_t)V * 20 * 4);
    float*  npj32    = (float*)alloc((size_t)V * 32 * 4);
    ushort* acat     = (ushort*)alloc((size_t)V * 512 * 2);
    ushort* nf_bf    = (ushort*)alloc((size_t)V * 256 * 2);
    ushort* ctx_bf   = (ushort*)alloc((size_t)V * 256 * 2);
    ushort* rz_bf    = (ushort*)alloc((size_t)V * 512 * 2);
    ushort* hv_bf    = rz_bf;  // alias: hv dead before rz GEMM writes
    ushort* in_bf    = (ushort*)alloc((size_t)V * 256 * 2);
    ushort* hn_bf    = (ushort*)alloc((size_t)V * 256 * 2);
    ushort* BTn      = (ushort*)alloc(65536 * 2);
    ushort* BTrz     = (ushort*)alloc(262144 * 2);
    ushort* BTin     = (ushort*)alloc(65536 * 2);
    ushort* BThn     = (ushort*)alloc(65536 * 2);
    ushort* BTc      = (ushort*)alloc(131072 * 2);
    ushort* BTp      = (ushort*)alloc(32768 * 2);
    float*  bias_rz  = (float*)alloc(512 * 4);
    float*  bp_pad   = (float*)alloc(128 * 4);
    float*  logitOrd = (float*)alloc((size_t)E * 4);
    int*    srcOrd   = (int*)alloc((size_t)E * 4);
    float*  pd       = (float*)alloc((size_t)V * 4);
    float*  ps       = (float*)alloc((size_t)V * 4);
    float*  mArr     = (float*)alloc((size_t)V * 4);
    float*  invArr   = (float*)alloc((size_t)V * 4);
    int*    deg      = (int*)alloc((size_t)V * 4);
    int*    cnt      = (int*)alloc((size_t)V * 4);
    int*    rowp     = (int*)alloc((size_t)(V + 1) * 4);
    int*    eorder   = (int*)alloc((size_t)E * 4);
    ushort* npj64    = (ushort*)alloc((size_t)V * 64 * 2);   // bf16, K padded to 64
    ushort* W2t      = (ushort*)alloc((size_t)5120 * 64 * 2);
    float*  zbias    = (float*)alloc(5120 * 4);

    // T chunk buffer ALIASED onto in_bf+hn_bf (contiguous 2 * V*256*2 = V*1024 bytes).
    // Those buffers are written only AFTER the kron loop completes, so the alias is safe
    // under stream ordering.  chunkV * 5120 * 2 <= V * 1024  =>  chunkV <= V/10.
    ushort* T_bf = in_bf;
    int chunkV = V / 10; if (chunkV < 1) chunkV = 1;

    hipMemsetAsync(deg, 0, (size_t)V * 4, stream);
    hipMemsetAsync(cnt, 0, (size_t)V * 4, stream);
    hipMemsetAsync(zbias, 0, 5120 * 4, stream);

    int mt = (V + 127) / 128;

    cast_bf16_kernel<<<(V * 64 + 255) / 256, 256, 0, stream>>>(nf, nf_bf, V * 256);
    prep_w_kernel<<<(950912 + 255) / 256, 256, 0, stream>>>(
        Wn, W_ih, W_hh, Wc, b_ih, b_hh, Wp, bp, Wk,
        BTn, BTrz, BTin, BThn, BTc, bias_rz, BTp, bp_pad, W2t);

    // npj32 = nf @ Wp + bp (N padded to 32, via 128-wide tile w/ zero rows)
    mfma_gemm_kernel<<<dim3(mt, 1), 256, 0, stream>>>(
        nf_bf, nf_bf, 256, 256, BTp, bp_pad, npj32, 0, V, 32, 256, 32);
    ln20_kernel<<<(V + 3) / 4, 256, 0, stream>>>(npj32, gp, betap, npj, npj64, V);

    deg_kernel<<<(E + 255) / 256, 256, 0, stream>>>(dst, deg, E);
    scan_kernel<<<1, 1024, 0, stream>>>(deg, rowp, V);
    scatter_kernel<<<(E + 255) / 256, 256, 0, stream>>>(dst, rowp, cnt, eorder, E);
    nodeproj_kernel<<<(V + 3) / 4, 256, 0, stream>>>(nf, We, pd, ps, V);
    edgeprep_kernel<<<(E + 255) / 256, 256, 0, stream>>>(
        eorder, src, dst, pd, ps, be, logitOrd, srcOrd, E);

    // hv = nf @ Wn + bn  -> bf16 (aliased on rz_bf; consumed by ctx before rz GEMM)
    mfma_gemm_kernel<<<dim3(mt, 2), 256, 0, stream>>>(
        nf_bf, nf_bf, 256, 256, BTn, bn, hv_bf, 1, V, 256, 256, 256);
    att_kernel<<<(V + 3) / 4, 256, 0, stream>>>(logitOrd, rowp, mArr, invArr, V);
    ctx_kernel<<<V, 256, 0, stream>>>(hv_bf, logitOrd, mArr, invArr, srcOrd, rowp, ctx_bf, V);

    // ---- kron branch: chunked {T-GEMM -> kron2}, T chunk L3-resident ----
    for (int vlo = 0; vlo < V; vlo += chunkV) {
        int vhi = vlo + chunkV; if (vhi > V) vhi = V;
        int cm = vhi - vlo;
        mfma_gemm_kernel<<<dim3((cm + 127) / 128, 40), 256, 0, stream>>>(
            npj64 + (size_t)vlo * 64, npj64 + (size_t)vlo * 64, 64, 64,
            W2t, zbias, T_bf, 1, cm, 5120, 64, 5120);
        kron2_kernel<<<(cm + KG - 1) / KG, 256, 0, stream>>>(
            npj, srcOrd, rowp, T_bf, bk, gk, betak, acat, vlo, vhi);
    }

    // rz = [ctx|nf] @ BTrz + (b_ih+b_hh)
    mfma_gemm_kernel<<<dim3(mt, 4), 256, 0, stream>>>(
        ctx_bf, nf_bf, 256, 256, BTrz, bias_rz, rz_bf, 1, V, 512, 512, 512);
    mfma_gemm_kernel<<<dim3(mt, 2), 256, 0, stream>>>(
        ctx_bf, ctx_bf, 256, 256, BTin, b_ih + 512, in_bf, 1, V, 256, 256, 256);
    mfma_gemm_kernel<<<dim3(mt, 2), 256, 0, stream>>>(
        nf_bf, nf_bf, 256, 256, BThn, b_hh + 512, hn_bf, 1, V, 256, 256, 256);

    gru_ln_kernel<<<V, 256, 0, stream>>>(rz_bf, in_bf, hn_bf, nf, g_ln, bt_ln, acat, V);

    mfma_gemm_kernel<<<dim3(mt, 2), 256, 0, stream>>>(
        acat, acat, 512, 512, BTc, bc, (float*)d_out, 0, V, 256, 512, 256);
    ln_kernel<<<V, 256, 0, stream>>>((float*)d_out, (float*)d_out, gc, betac, 1);
}

// Round 8
// 1226.533 us; speedup vs baseline: 1.1872x; 1.1872x over previous
//
#include <hip/hip_runtime.h>
#include <hip/hip_bf16.h>
#include <math.h>

#define KG 8         // dst nodes per block in kron kernel (one per wave, 512 threads)
#define KTHR 512
#define KCHUNK 128   // edges staged in LDS per kron chunk

typedef __attribute__((ext_vector_type(8))) short bfrag;   // 8 bf16 (4 VGPRs)
typedef __attribute__((ext_vector_type(4))) float cfrag;   // 4 fp32 acc
typedef _Float16 __attribute__((ext_vector_type(2))) half2v;

__device__ __forceinline__ ushort f2bf(float f) {
    __hip_bfloat16 h = __float2bfloat16(f);
    return *(ushort*)&h;
}
__device__ __forceinline__ float bf2f(ushort u) {
    __hip_bfloat16 h;
    *(ushort*)&h = u;
    return __bfloat162float(h);
}
__device__ __forceinline__ uint packf16(float lo, float hi) {
    _Float16 l = (_Float16)lo, h = (_Float16)hi;
    ushort ul = *(ushort*)&l, uh = *(ushort*)&h;
    return (uint)ul | ((uint)uh << 16);
}

// ---------------------------------------------------------------- helpers
__device__ __forceinline__ void blockSum2(float& s1, float& s2, float* red) {
    #pragma unroll
    for (int off = 32; off > 0; off >>= 1) {
        s1 += __shfl_xor(s1, off);
        s2 += __shfl_xor(s2, off);
    }
    int lane = threadIdx.x & 63, wid = threadIdx.x >> 6;
    if (lane == 0) { red[wid] = s1; red[4 + wid] = s2; }
    __syncthreads();
    s1 = red[0] + red[1] + red[2] + red[3];
    s2 = red[4] + red[5] + red[6] + red[7];
}

// VALU-only full-wave sum: DPP row_shr 1/2/4/8 + row_bcast15/31, result via readlane(63).
__device__ __forceinline__ float dppWaveSum(float x) {
    float t;
    t = __int_as_float(__builtin_amdgcn_update_dpp(0, __float_as_int(x), 0x111, 0xf, 0xf, true)); x += t;
    t = __int_as_float(__builtin_amdgcn_update_dpp(0, __float_as_int(x), 0x112, 0xf, 0xf, true)); x += t;
    t = __int_as_float(__builtin_amdgcn_update_dpp(0, __float_as_int(x), 0x114, 0xf, 0xf, true)); x += t;
    t = __int_as_float(__builtin_amdgcn_update_dpp(0, __float_as_int(x), 0x118, 0xf, 0xf, true)); x += t;
    t = __int_as_float(__builtin_amdgcn_update_dpp(0, __float_as_int(x), 0x142, 0xf, 0xf, true)); x += t;
    t = __int_as_float(__builtin_amdgcn_update_dpp(0, __float_as_int(x), 0x143, 0xf, 0xf, true)); x += t;
    return __int_as_float(__builtin_amdgcn_readlane(__float_as_int(x), 63));
}

__device__ __forceinline__ float sigmoidf(float x) { return 1.0f / (1.0f + expf(-x)); }

// ---------------------------------------------------------------- bf16 cast
__global__ __launch_bounds__(256) void cast_bf16_kernel(
    const float* __restrict__ x, ushort* __restrict__ y, int n)
{
    int i = (blockIdx.x * 256 + threadIdx.x) * 4;
    if (i < n) {
        float4 v = *(const float4*)(x + i);
        ushort4 o;
        o.x = f2bf(v.x); o.y = f2bf(v.y); o.z = f2bf(v.z); o.w = f2bf(v.w);
        *(ushort4*)(y + i) = o;
    }
}

// ---------------------------------------------------------------- weight prep (bf16 B^T layouts + f16-packed Wk)
__global__ __launch_bounds__(256) void prep_w_kernel(
    const float* __restrict__ Wn, const float* __restrict__ Wih,
    const float* __restrict__ Whh, const float* __restrict__ Wc,
    const float* __restrict__ b_ih, const float* __restrict__ b_hh,
    const float* __restrict__ Wp, const float* __restrict__ bp,
    const float* __restrict__ Wk,
    ushort* __restrict__ BTn, ushort* __restrict__ BTrz,
    ushort* __restrict__ BTin, ushort* __restrict__ BThn,
    ushort* __restrict__ BTc, float* __restrict__ bias_rz,
    ushort* __restrict__ BTp, float* __restrict__ bp_pad,
    uint* __restrict__ Wkp)
{
    int id = blockIdx.x * 256 + threadIdx.x;
    if (id < 262144) {
        int n = id >> 9, k = id & 511;
        float v = (k < 256) ? Wih[n * 256 + k] : Whh[n * 256 + k - 256];
        BTrz[id] = f2bf(v);
    } else if (id < 327680) {
        int j = id - 262144; int n = j >> 8, k = j & 255;
        BTin[j] = f2bf(Wih[(512 + n) * 256 + k]);
    } else if (id < 393216) {
        int j = id - 327680; int n = j >> 8, k = j & 255;
        BThn[j] = f2bf(Whh[(512 + n) * 256 + k]);
    } else if (id < 458752) {
        int j = id - 393216; int n = j >> 8, k = j & 255;
        BTn[j] = f2bf(Wn[k * 256 + n]);
    } else if (id < 589824) {
        int j = id - 458752; int n = j >> 9, k = j & 511;
        BTc[j] = f2bf(Wc[k * 256 + n]);
    } else if (id < 590336) {
        int n = id - 589824;
        bias_rz[n] = b_ih[n] + b_hh[n];
    } else if (id < 623104) {
        int j = id - 590336; int n = j >> 8, k = j & 255;
        BTp[j] = f2bf((n < 20) ? Wp[k * 20 + n] : 0.f);
    } else if (id < 623232) {
        int n = id - 623104;
        bp_pad[n] = (n < 20) ? bp[n] : 0.f;
    } else if (id < 674432) {
        // Wkp[(a*10+kk)*256 + o] = packf16(Wk[(a*20+2kk)][o], Wk[(a*20+2kk+1)][o])
        int j = id - 623232;
        int row = j >> 8, o = j & 255;
        int a = row / 10, kk = row - a * 10;
        float lo = Wk[(size_t)(a * 20 + 2 * kk) * 256 + o];
        float hi = Wk[(size_t)(a * 20 + 2 * kk + 1) * 256 + o];
        Wkp[j] = packf16(lo, hi);
    }
}

// ---------------------------------------------------------------- generic bf16 MFMA GEMM (128x128, BK=64)
__global__ __launch_bounds__(256) void mfma_gemm_kernel(
    const ushort* __restrict__ A1, const ushort* __restrict__ A2, int ksplit, int lda,
    const ushort* __restrict__ B, const float* __restrict__ bias,
    void* __restrict__ Cout, int store_bf16,
    int M, int N, int K, int ldc)
{
    __shared__ ushort As[128 * 64];
    __shared__ ushort Bs[128 * 64];
    int t = threadIdx.x;
    int m0 = blockIdx.x * 128, n0 = blockIdx.y * 128;
    int w = t >> 6, lane = t & 63;
    int q = lane >> 4, r = lane & 15;
    int wm = (w & 1) * 64, wn = (w >> 1) * 64;

    cfrag acc[4][4] = {};

    int srow_base = t >> 3;
    int skc = t & 7;

    for (int k0 = 0; k0 < K; k0 += 64) {
        const ushort* Ap; int kb;
        if (k0 < ksplit) { Ap = A1; kb = k0; } else { Ap = A2; kb = k0 - ksplit; }
        int4 av[4], bv[4];
        #pragma unroll
        for (int i = 0; i < 4; ++i) {
            int row = i * 32 + srow_base;
            int grow = m0 + row;
            av[i] = make_int4(0, 0, 0, 0);
            if (grow < M) av[i] = *(const int4*)(Ap + (size_t)grow * lda + kb + skc * 8);
            bv[i] = *(const int4*)(B + (size_t)(n0 + row) * K + k0 + skc * 8);
        }
        __syncthreads();
        #pragma unroll
        for (int i = 0; i < 4; ++i) {
            int row = i * 32 + srow_base;
            int off = row * 64 + ((skc ^ (row & 7)) * 8);
            *(int4*)&As[off] = av[i];
            *(int4*)&Bs[off] = bv[i];
        }
        __syncthreads();
        #pragma unroll
        for (int s = 0; s < 2; ++s) {
            bfrag af[4], bfr[4];
            int kc = s * 4 + q;
            #pragma unroll
            for (int mi = 0; mi < 4; ++mi) {
                int arow = wm + mi * 16 + r;
                af[mi] = *(const bfrag*)&As[arow * 64 + ((kc ^ (arow & 7)) * 8)];
            }
            #pragma unroll
            for (int ni = 0; ni < 4; ++ni) {
                int brow = wn + ni * 16 + r;
                bfr[ni] = *(const bfrag*)&Bs[brow * 64 + ((kc ^ (brow & 7)) * 8)];
            }
            #pragma unroll
            for (int mi = 0; mi < 4; ++mi)
                #pragma unroll
                for (int ni = 0; ni < 4; ++ni)
                    acc[mi][ni] = __builtin_amdgcn_mfma_f32_16x16x32_bf16(
                        af[mi], bfr[ni], acc[mi][ni], 0, 0, 0);
        }
    }

    float bvld[4];
    #pragma unroll
    for (int ni = 0; ni < 4; ++ni) bvld[ni] = bias[n0 + wn + ni * 16 + r];
    #pragma unroll
    for (int mi = 0; mi < 4; ++mi) {
        #pragma unroll
        for (int v = 0; v < 4; ++v) {
            int grow = m0 + wm + mi * 16 + q * 4 + v;
            if (grow >= M) continue;
            #pragma unroll
            for (int ni = 0; ni < 4; ++ni) {
                int gcol = n0 + wn + ni * 16 + r;
                if (gcol >= N) continue;
                float val = acc[mi][ni][v] + bvld[ni];
                if (store_bf16) ((ushort*)Cout)[(size_t)grow * ldc + gcol] = f2bf(val);
                else            ((float*)Cout)[(size_t)grow * ldc + gcol] = val;
            }
        }
    }
}

// ---------------------------------------------------------------- LN(20)+relu on npj32 [V,32] -> npj [V,20]
__global__ __launch_bounds__(256) void ln20_kernel(
    const float* __restrict__ npj32, const float* __restrict__ gp,
    const float* __restrict__ betap, float* __restrict__ npj, int V)
{
    int wid = threadIdx.x >> 6, j = threadIdx.x & 63;
    int v = blockIdx.x * 4 + wid;
    if (v >= V) return;
    float acc = (j < 20) ? npj32[(size_t)v * 32 + j] : 0.f;
    float s1 = acc, s2 = acc * acc;
    #pragma unroll
    for (int off = 32; off > 0; off >>= 1) {
        s1 += __shfl_xor(s1, off);
        s2 += __shfl_xor(s2, off);
    }
    float mu = s1 * (1.0f / 20.0f);
    float var = s2 * (1.0f / 20.0f) - mu * mu;
    if (j < 20) {
        float y = (acc - mu) * rsqrtf(var + 1e-5f) * gp[j] + betap[j];
        npj[(size_t)v * 20 + j] = fmaxf(y, 0.f);
    }
}

// ---------------------------------------------------------------- CSR build
__global__ __launch_bounds__(256) void deg_kernel(const int* __restrict__ dst, int* __restrict__ deg, int E) {
    int e = blockIdx.x * 256 + threadIdx.x;
    if (e < E) atomicAdd(&deg[dst[e]], 1);
}

__global__ __launch_bounds__(1024) void scan_kernel(const int* __restrict__ deg, int* __restrict__ row, int V) {
    __shared__ int wsum[16];
    __shared__ int carry_sh;
    int t = threadIdx.x, lane = t & 63, wid = t >> 6;
    if (t == 0) carry_sh = 0;
    __syncthreads();
    for (int base = 0; base < V; base += 1024) {
        int i = base + t;
        int val = (i < V) ? deg[i] : 0;
        #pragma unroll
        for (int s = 1; s < 64; s <<= 1) {
            int n = __shfl_up(val, s);
            if (lane >= s) val += n;
        }
        if (lane == 63) wsum[wid] = val;
        __syncthreads();
        if (wid == 0) {
            int x = (lane < 16) ? wsum[lane] : 0;
            #pragma unroll
            for (int s = 1; s < 16; s <<= 1) {
                int n = __shfl_up(x, s);
                if (lane >= s) x += n;
            }
            if (lane < 16) wsum[lane] = x;
        }
        __syncthreads();
        int wprefix = (wid > 0) ? wsum[wid - 1] : 0;
        int c = carry_sh;
        int incl = c + wprefix + val;
        if (i < V) row[i + 1] = incl;
        __syncthreads();
        if (t == 1023) carry_sh = incl;
    }
    if (t == 0) row[0] = 0;
}

__global__ __launch_bounds__(256) void scatter_kernel(
    const int* __restrict__ dst, const int* __restrict__ row,
    int* __restrict__ cnt, int* __restrict__ eorder, int E)
{
    int e = blockIdx.x * 256 + threadIdx.x;
    if (e < E) {
        int d = dst[e];
        int pos = row[d] + atomicAdd(&cnt[d], 1);
        eorder[pos] = e;
    }
}

// ---------------------------------------------------------------- per-node edge-logit projections
__global__ __launch_bounds__(256) void nodeproj_kernel(
    const float* __restrict__ nf, const float* __restrict__ We,
    float* __restrict__ pd, float* __restrict__ ps, int V)
{
    int wid = threadIdx.x >> 6, lane = threadIdx.x & 63;
    int v = blockIdx.x * 4 + wid;
    if (v >= V) return;
    const float* row = nf + (size_t)v * 256;
    int i = lane * 4;
    float4 x  = *(const float4*)(row + i);
    float4 wd = *(const float4*)(We + i);
    float4 wsv = *(const float4*)(We + 256 + i);
    float sd = x.x * wd.x + x.y * wd.y + x.z * wd.z + x.w * wd.w;
    float ss = x.x * wsv.x + x.y * wsv.y + x.z * wsv.z + x.w * wsv.w;
    #pragma unroll
    for (int off = 32; off > 0; off >>= 1) {
        sd += __shfl_xor(sd, off);
        ss += __shfl_xor(ss, off);
    }
    if (lane == 0) { pd[v] = sd; ps[v] = ss; }
}

// ---------------------------------------------------------------- edge prep (eorder order)
__global__ __launch_bounds__(256) void edgeprep_kernel(
    const int* __restrict__ eorder, const int* __restrict__ src, const int* __restrict__ dst,
    const float* __restrict__ pd, const float* __restrict__ ps, const float* __restrict__ be,
    float* __restrict__ logitOrd, int* __restrict__ srcOrd, int E)
{
    int p = blockIdx.x * 256 + threadIdx.x;
    if (p < E) {
        int e = eorder[p];
        int s = src[e], d = dst[e];
        srcOrd[p] = s;
        logitOrd[p] = fmaxf(pd[d] + ps[s] + be[0], 0.f);
    }
}

// ---------------------------------------------------------------- kron branch (fused, KG=8 via f16 dot2 stage-1)
// Stage 1: 512 threads; thread (c = t&255, h = t>>6? no: h = t>>8) computes T[(g,a)][c] for
// a in h's half-range via v_dot2_f32_f16 on f16-packed d (dreg[8][10] uints, 80 VGPR) and
// f16-packed Wk rows (10 dword loads per a).  Block streams Wkp exactly once (205 KB / 8 dsts).
// Stage 2: one wave per dst (8 waves), IDENTICAL to the proven edge loop: chunked sE LDS
// staging, float4 reads, DPP LN reductions, per-wave accumulate.
__global__ __launch_bounds__(KTHR) void kron_kernel(
    const float* __restrict__ npj, const int* __restrict__ srcOrd,
    const int* __restrict__ rowPtr,
    const uint* __restrict__ Wkp, const float* __restrict__ bk,
    const float* __restrict__ gkv, const float* __restrict__ betak,
    ushort* __restrict__ acat, int V)
{
    __shared__ __hip_bfloat16 T[KG * 20 * 256];   // 80 KB
    __shared__ uint dshp[KG * 10];                // f16-packed d
    __shared__ float sE[KCHUNK * 20];             // 10 KB
    int t = threadIdx.x;
    int v0 = blockIdx.x * KG;

    if (t < KG * 10) {
        int g = t / 10, kk = t - g * 10;
        int v = v0 + g;
        float lo = 0.f, hi = 0.f;
        if (v < V) {
            lo = npj[(size_t)v * 20 + 2 * kk];
            hi = npj[(size_t)v * 20 + 2 * kk + 1];
        }
        dshp[t] = packf16(lo, hi);
    }
    __syncthreads();

    // ---- stage 1
    {
        uint dreg[KG][10];
        #pragma unroll
        for (int g = 0; g < KG; ++g)
            #pragma unroll
            for (int kk = 0; kk < 10; ++kk) dreg[g][kk] = dshp[g * 10 + kk];

        int c = t & 255, h = t >> 8;   // h in {0,1}
        int a0 = h * 10;
        for (int a = a0; a < a0 + 10; ++a) {
            uint wv[10];
            #pragma unroll
            for (int kk = 0; kk < 10; ++kk)
                wv[kk] = Wkp[(size_t)(a * 10 + kk) * 256 + c];
            #pragma unroll
            for (int g = 0; g < KG; ++g) {
                float s = 0.f;
                #pragma unroll
                for (int kk = 0; kk < 10; ++kk) {
                    half2v d2 = *(half2v*)&dreg[g][kk];
                    half2v w2 = *(half2v*)&wv[kk];
                    s = __builtin_amdgcn_fdot2(d2, w2, s, false);
                }
                T[(g * 20 + a) * 256 + c] = __float2bfloat16(s);
            }
        }
    }
    __syncthreads();

    // ---- stage 2 (proven edge loop)
    int wid = t >> 6, lane = t & 63;
    int v = v0 + wid;
    int c0 = lane * 4;

    float Tr[20][4];
    #pragma unroll
    for (int a = 0; a < 20; ++a) {
        const __hip_bfloat16* tp = &T[(wid * 20 + a) * 256 + c0];
        Tr[a][0] = __bfloat162float(tp[0]);
        Tr[a][1] = __bfloat162float(tp[1]);
        Tr[a][2] = __bfloat162float(tp[2]);
        Tr[a][3] = __bfloat162float(tp[3]);
    }
    float4 bkv = *(const float4*)(bk + c0);
    float4 gk4 = *(const float4*)(gkv + c0);
    float4 bt4 = *(const float4*)(betak + c0);

    int eBase = rowPtr[v0];
    int vEnd = (v0 + KG < V) ? (v0 + KG) : V;
    int eEndB = rowPtr[vEnd];
    int myE0 = (v < V) ? rowPtr[v] : 0;
    int myE1 = (v < V) ? rowPtr[v + 1] : 0;

    float a0 = 0.f, a1 = 0.f, a2 = 0.f, a3 = 0.f;

    for (int base = eBase; base < eEndB; base += KCHUNK) {
        int nC = eEndB - base; if (nC > KCHUNK) nC = KCHUNK;
        __syncthreads();   // previous chunk fully consumed
        for (int idx = t; idx < nC * 20; idx += KTHR) {
            int le = idx / 20, aa = idx - le * 20;
            sE[idx] = npj[(size_t)srcOrd[base + le] * 20 + aa];
        }
        __syncthreads();

        int lo = (myE0 > base) ? myE0 : base;
        int hi = (myE1 < base + nC) ? myE1 : base + nC;
        int p = lo;
        for (; p + 1 < hi; p += 2) {
            const float* sa = &sE[(p - base) * 20];
            const float* sb = &sE[(p + 1 - base) * 20];
            float4 sa0 = *(const float4*)(sa);
            float4 sa1 = *(const float4*)(sa + 4);
            float4 sa2 = *(const float4*)(sa + 8);
            float4 sa3 = *(const float4*)(sa + 12);
            float4 sa4 = *(const float4*)(sa + 16);
            float4 sb0 = *(const float4*)(sb);
            float4 sb1 = *(const float4*)(sb + 4);
            float4 sb2 = *(const float4*)(sb + 8);
            float4 sb3 = *(const float4*)(sb + 12);
            float4 sb4 = *(const float4*)(sb + 16);
            float sav[20] = {sa0.x, sa0.y, sa0.z, sa0.w, sa1.x, sa1.y, sa1.z, sa1.w,
                             sa2.x, sa2.y, sa2.z, sa2.w, sa3.x, sa3.y, sa3.z, sa3.w,
                             sa4.x, sa4.y, sa4.z, sa4.w};
            float sbv[20] = {sb0.x, sb0.y, sb0.z, sb0.w, sb1.x, sb1.y, sb1.z, sb1.w,
                             sb2.x, sb2.y, sb2.z, sb2.w, sb3.x, sb3.y, sb3.z, sb3.w,
                             sb4.x, sb4.y, sb4.z, sb4.w};
            float ya0 = bkv.x, ya1 = bkv.y, ya2 = bkv.z, ya3 = bkv.w;
            float yb0 = bkv.x, yb1 = bkv.y, yb2 = bkv.z, yb3 = bkv.w;
            #pragma unroll
            for (int a = 0; a < 20; ++a) {
                float va = sav[a], vb = sbv[a];
                ya0 += va * Tr[a][0]; ya1 += va * Tr[a][1];
                ya2 += va * Tr[a][2]; ya3 += va * Tr[a][3];
                yb0 += vb * Tr[a][0]; yb1 += vb * Tr[a][1];
                yb2 += vb * Tr[a][2]; yb3 += vb * Tr[a][3];
            }
            float s1a = dppWaveSum(ya0 + ya1 + ya2 + ya3);
            float s2a = dppWaveSum(ya0 * ya0 + ya1 * ya1 + ya2 * ya2 + ya3 * ya3);
            float s1b = dppWaveSum(yb0 + yb1 + yb2 + yb3);
            float s2b = dppWaveSum(yb0 * yb0 + yb1 * yb1 + yb2 * yb2 + yb3 * yb3);
            float mua = s1a * (1.0f / 256.0f);
            float rsa = rsqrtf(s2a * (1.0f / 256.0f) - mua * mua + 1e-5f);
            float mub = s1b * (1.0f / 256.0f);
            float rsb = rsqrtf(s2b * (1.0f / 256.0f) - mub * mub + 1e-5f);
            a0 += fmaxf((ya0 - mua) * rsa * gk4.x + bt4.x, 0.f) + fmaxf((yb0 - mub) * rsb * gk4.x + bt4.x, 0.f);
            a1 += fmaxf((ya1 - mua) * rsa * gk4.y + bt4.y, 0.f) + fmaxf((yb1 - mub) * rsb * gk4.y + bt4.y, 0.f);
            a2 += fmaxf((ya2 - mua) * rsa * gk4.z + bt4.z, 0.f) + fmaxf((yb2 - mub) * rsb * gk4.z + bt4.z, 0.f);
            a3 += fmaxf((ya3 - mua) * rsa * gk4.w + bt4.w, 0.f) + fmaxf((yb3 - mub) * rsb * gk4.w + bt4.w, 0.f);
        }
        if (p < hi) {
            const float* sa = &sE[(p - base) * 20];
            float4 sa0 = *(const float4*)(sa);
            float4 sa1 = *(const float4*)(sa + 4);
            float4 sa2 = *(const float4*)(sa + 8);
            float4 sa3 = *(const float4*)(sa + 12);
            float4 sa4 = *(const float4*)(sa + 16);
            float sav[20] = {sa0.x, sa0.y, sa0.z, sa0.w, sa1.x, sa1.y, sa1.z, sa1.w,
                             sa2.x, sa2.y, sa2.z, sa2.w, sa3.x, sa3.y, sa3.z, sa3.w,
                             sa4.x, sa4.y, sa4.z, sa4.w};
            float ya0 = bkv.x, ya1 = bkv.y, ya2 = bkv.z, ya3 = bkv.w;
            #pragma unroll
            for (int a = 0; a < 20; ++a) {
                float va = sav[a];
                ya0 += va * Tr[a][0]; ya1 += va * Tr[a][1];
                ya2 += va * Tr[a][2]; ya3 += va * Tr[a][3];
            }
            float s1a = dppWaveSum(ya0 + ya1 + ya2 + ya3);
            float s2a = dppWaveSum(ya0 * ya0 + ya1 * ya1 + ya2 * ya2 + ya3 * ya3);
            float mua = s1a * (1.0f / 256.0f);
            float rsa = rsqrtf(s2a * (1.0f / 256.0f) - mua * mua + 1e-5f);
            a0 += fmaxf((ya0 - mua) * rsa * gk4.x + bt4.x, 0.f);
            a1 += fmaxf((ya1 - mua) * rsa * gk4.y + bt4.y, 0.f);
            a2 += fmaxf((ya2 - mua) * rsa * gk4.z + bt4.z, 0.f);
            a3 += fmaxf((ya3 - mua) * rsa * gk4.w + bt4.w, 0.f);
        }
    }
    if (v < V) {
        ushort4 o;
        o.x = f2bf(a0); o.y = f2bf(a1); o.z = f2bf(a2); o.w = f2bf(a3);
        *(ushort4*)(acat + (size_t)v * 512 + 256 + c0) = o;
    }
}

// ---------------------------------------------------------------- attention stats per dst (linear reads)
__global__ __launch_bounds__(256) void att_kernel(
    const float* __restrict__ logitOrd, const int* __restrict__ rowPtr,
    float* __restrict__ mArr, float* __restrict__ invArr, int V)
{
    int wid = threadIdx.x >> 6, lane = threadIdx.x & 63;
    int v = blockIdx.x * 4 + wid;
    if (v >= V) return;
    int e0 = rowPtr[v], e1 = rowPtr[v + 1];
    float m = -1e30f;
    for (int p = e0 + lane; p < e1; p += 64) m = fmaxf(m, logitOrd[p]);
    #pragma unroll
    for (int off = 32; off > 0; off >>= 1) m = fmaxf(m, __shfl_xor(m, off));
    float d = 0.f;
    for (int p = e0 + lane; p < e1; p += 64) d += expf(logitOrd[p] - m);
    #pragma unroll
    for (int off = 32; off > 0; off >>= 1) d += __shfl_xor(d, off);
    if (lane == 0) {
        mArr[v] = m;
        invArr[v] = (e1 > e0) ? (1.0f / d) : 0.f;
    }
}

// ---------------------------------------------------------------- weighted context (bf16 hv, unroll x4)
__global__ __launch_bounds__(256) void ctx_kernel(
    const ushort* __restrict__ hv_bf, const float* __restrict__ logitOrd,
    const float* __restrict__ mArr, const float* __restrict__ invArr,
    const int* __restrict__ srcOrd, const int* __restrict__ rowPtr,
    ushort* __restrict__ ctx_bf, int V)
{
    int v = blockIdx.x;
    int t = threadIdx.x;
    int e0 = rowPtr[v], e1 = rowPtr[v + 1];
    float m = mArr[v], inv = invArr[v];
    float acc = 0.f;
    int p = e0;
    for (; p + 3 < e1; p += 4) {
        int s0 = srcOrd[p], s1 = srcOrd[p + 1], s2 = srcOrd[p + 2], s3 = srcOrd[p + 3];
        float w0 = expf(logitOrd[p] - m) * inv;
        float w1 = expf(logitOrd[p + 1] - m) * inv;
        float w2 = expf(logitOrd[p + 2] - m) * inv;
        float w3 = expf(logitOrd[p + 3] - m) * inv;
        float h0 = bf2f(hv_bf[(size_t)s0 * 256 + t]);
        float h1 = bf2f(hv_bf[(size_t)s1 * 256 + t]);
        float h2 = bf2f(hv_bf[(size_t)s2 * 256 + t]);
        float h3 = bf2f(hv_bf[(size_t)s3 * 256 + t]);
        acc += w0 * h0 + w1 * h1 + w2 * h2 + w3 * h3;
    }
    for (; p < e1; ++p) {
        float wgt = expf(logitOrd[p] - m) * inv;
        acc += wgt * bf2f(hv_bf[(size_t)srcOrd[p] * 256 + t]);
    }
    ctx_bf[(size_t)v * 256 + t] = f2bf(fmaxf(acc, 0.f));
}

// ---------------------------------------------------------------- GRU gates + LN -> bf16 into acat[:,0:256]
__global__ __launch_bounds__(256) void gru_ln_kernel(
    const ushort* __restrict__ rz, const ushort* __restrict__ inb,
    const ushort* __restrict__ hnb, const float* __restrict__ nf,
    const float* __restrict__ g_ln, const float* __restrict__ b_ln,
    ushort* __restrict__ acat, int V)
{
    __shared__ float red[8];
    int v = blockIdx.x, t = threadIdx.x;
    float r = sigmoidf(bf2f(rz[(size_t)v * 512 + t]));
    float z = sigmoidf(bf2f(rz[(size_t)v * 512 + 256 + t]));
    float n = tanhf(bf2f(inb[(size_t)v * 256 + t]) + r * bf2f(hnb[(size_t)v * 256 + t]));
    float h = (1.f - z) * n + z * nf[(size_t)v * 256 + t];
    float x = fmaxf(h, 0.f);
    float s1 = x, s2 = x * x;
    blockSum2(s1, s2, red);
    float mu = s1 * (1.0f / 256.0f);
    float var = s2 * (1.0f / 256.0f) - mu * mu;
    float y = (x - mu) * rsqrtf(var + 1e-5f) * g_ln[t] + b_ln[t];
    acat[(size_t)v * 512 + t] = f2bf(y);
}

// ---------------------------------------------------------------- row LayerNorm (optional relu)
__global__ __launch_bounds__(256) void ln_kernel(
    const float* __restrict__ in, float* __restrict__ out,
    const float* __restrict__ g, const float* __restrict__ b, int relu_after)
{
    __shared__ float red[8];
    int v = blockIdx.x, t = threadIdx.x;
    float x = in[(size_t)v * 256 + t];
    float s1 = x, s2 = x * x;
    blockSum2(s1, s2, red);
    float mu = s1 * (1.0f / 256.0f);
    float var = s2 * (1.0f / 256.0f) - mu * mu;
    float y = (x - mu) * rsqrtf(var + 1e-5f) * g[t] + b[t];
    if (relu_after) y = fmaxf(y, 0.f);
    out[(size_t)v * 256 + t] = y;
}

// ---------------------------------------------------------------- launcher
extern "C" void kernel_launch(void* const* d_in, const int* in_sizes, int n_in,
                              void* d_out, int out_size, void* d_ws, size_t ws_size,
                              hipStream_t stream)
{
    const float* nf    = (const float*)d_in[0];
    const int*   src   = (const int*)d_in[1];
    const int*   dst   = (const int*)d_in[2];
    const float* Wp    = (const float*)d_in[3];
    const float* bp    = (const float*)d_in[4];
    const float* gp    = (const float*)d_in[5];
    const float* betap = (const float*)d_in[6];
    const float* Wk    = (const float*)d_in[7];
    const float* bk    = (const float*)d_in[8];
    const float* gk    = (const float*)d_in[9];
    const float* betak = (const float*)d_in[10];
    const float* We    = (const float*)d_in[11];
    const float* be    = (const float*)d_in[12];
    const float* Wn    = (const float*)d_in[13];
    const float* bn    = (const float*)d_in[14];
    const float* W_ih  = (const float*)d_in[15];
    const float* W_hh  = (const float*)d_in[16];
    const float* b_ih  = (const float*)d_in[17];
    const float* b_hh  = (const float*)d_in[18];
    const float* g_ln  = (const float*)d_in[19];
    const float* bt_ln = (const float*)d_in[20];
    const float* Wc    = (const float*)d_in[21];
    const float* bc    = (const float*)d_in[22];
    const float* gc    = (const float*)d_in[23];
    const float* betac = (const float*)d_in[24];

    int V = in_sizes[0] / 256;
    int E = in_sizes[1];

    char* w = (char*)d_ws;
    auto alloc = [&](size_t bytes) -> char* {
        char* p = w;
        w += (bytes + 255) & ~(size_t)255;
        return p;
    };
    float*  npj      = (float*)alloc((size_t)V * 20 * 4);
    float*  npj32    = (float*)alloc((size_t)V * 32 * 4);
    ushort* acat     = (ushort*)alloc((size_t)V * 512 * 2);
    ushort* nf_bf    = (ushort*)alloc((size_t)V * 256 * 2);
    ushort* ctx_bf   = (ushort*)alloc((size_t)V * 256 * 2);
    ushort* rz_bf    = (ushort*)alloc((size_t)V * 512 * 2);
    ushort* hv_bf    = rz_bf;  // alias: hv dead before rz GEMM writes
    ushort* in_bf    = (ushort*)alloc((size_t)V * 256 * 2);
    ushort* hn_bf    = (ushort*)alloc((size_t)V * 256 * 2);
    ushort* BTn      = (ushort*)alloc(65536 * 2);
    ushort* BTrz     = (ushort*)alloc(262144 * 2);
    ushort* BTin     = (ushort*)alloc(65536 * 2);
    ushort* BThn     = (ushort*)alloc(65536 * 2);
    ushort* BTc      = (ushort*)alloc(131072 * 2);
    ushort* BTp      = (ushort*)alloc(32768 * 2);
    float*  bias_rz  = (float*)alloc(512 * 4);
    float*  bp_pad   = (float*)alloc(128 * 4);
    float*  logitOrd = (float*)alloc((size_t)E * 4);
    int*    srcOrd   = (int*)alloc((size_t)E * 4);
    float*  pd       = (float*)alloc((size_t)V * 4);
    float*  ps       = (float*)alloc((size_t)V * 4);
    float*  mArr     = (float*)alloc((size_t)V * 4);
    float*  invArr   = (float*)alloc((size_t)V * 4);
    int*    deg      = (int*)alloc((size_t)V * 4);
    int*    cnt      = (int*)alloc((size_t)V * 4);
    int*    rowp     = (int*)alloc((size_t)(V + 1) * 4);
    int*    eorder   = (int*)alloc((size_t)E * 4);
    uint*   Wkp      = (uint*)alloc((size_t)51200 * 4);   // f16-packed Wk [200][256]

    hipMemsetAsync(deg, 0, (size_t)V * 4, stream);
    hipMemsetAsync(cnt, 0, (size_t)V * 4, stream);

    int mt = (V + 127) / 128;

    cast_bf16_kernel<<<(V * 64 + 255) / 256, 256, 0, stream>>>(nf, nf_bf, V * 256);
    prep_w_kernel<<<(674432 + 255) / 256, 256, 0, stream>>>(
        Wn, W_ih, W_hh, Wc, b_ih, b_hh, Wp, bp, Wk,
        BTn, BTrz, BTin, BThn, BTc, bias_rz, BTp, bp_pad, Wkp);

    // npj32 = nf @ Wp + bp (N padded to 32, via 128-wide tile w/ zero rows)
    mfma_gemm_kernel<<<dim3(mt, 1), 256, 0, stream>>>(
        nf_bf, nf_bf, 256, 256, BTp, bp_pad, npj32, 0, V, 32, 256, 32);
    ln20_kernel<<<(V + 3) / 4, 256, 0, stream>>>(npj32, gp, betap, npj, V);

    deg_kernel<<<(E + 255) / 256, 256, 0, stream>>>(dst, deg, E);
    scan_kernel<<<1, 1024, 0, stream>>>(deg, rowp, V);
    scatter_kernel<<<(E + 255) / 256, 256, 0, stream>>>(dst, rowp, cnt, eorder, E);
    nodeproj_kernel<<<(V + 3) / 4, 256, 0, stream>>>(nf, We, pd, ps, V);
    edgeprep_kernel<<<(E + 255) / 256, 256, 0, stream>>>(
        eorder, src, dst, pd, ps, be, logitOrd, srcOrd, E);

    // hv = nf @ Wn + bn  -> bf16 (aliased on rz_bf; consumed by ctx before rz GEMM)
    mfma_gemm_kernel<<<dim3(mt, 2), 256, 0, stream>>>(
        nf_bf, nf_bf, 256, 256, BTn, bn, hv_bf, 1, V, 256, 256, 256);
    att_kernel<<<(V + 3) / 4, 256, 0, stream>>>(logitOrd, rowp, mArr, invArr, V);
    ctx_kernel<<<V, 256, 0, stream>>>(hv_bf, logitOrd, mArr, invArr, srcOrd, rowp, ctx_bf, V);

    kron_kernel<<<(V + KG - 1) / KG, KTHR, 0, stream>>>(
        npj, srcOrd, rowp, Wkp, bk, gk, betak, acat, V);

    // rz = [ctx|nf] @ BTrz + (b_ih+b_hh)
    mfma_gemm_kernel<<<dim3(mt, 4), 256, 0, stream>>>(
        ctx_bf, nf_bf, 256, 256, BTrz, bias_rz, rz_bf, 1, V, 512, 512, 512);
    mfma_gemm_kernel<<<dim3(mt, 2), 256, 0, stream>>>(
        ctx_bf, ctx_bf, 256, 256, BTin, b_ih + 512, in_bf, 1, V, 256, 256, 256);
    mfma_gemm_kernel<<<dim3(mt, 2), 256, 0, stream>>>(
        nf_bf, nf_bf, 256, 256, BThn, b_hh + 512, hn_bf, 1, V, 256, 256, 256);

    gru_ln_kernel<<<V, 256, 0, stream>>>(rz_bf, in_bf, hn_bf, nf, g_ln, bt_ln, acat, V);

    mfma_gemm_kernel<<<dim3(mt, 2), 256, 0, stream>>>(
        acat, acat, 512, 512, BTc, bc, (float*)d_out, 0, V, 256, 512, 256);
    ln_kernel<<<V, 256, 0, stream>>>((float*)d_out, (float*)d_out, gc, betac, 1);
}

// Round 10
// 1118.591 us; speedup vs baseline: 1.3018x; 1.0965x over previous
//
#include <hip/hip_runtime.h>
#include <hip/hip_bf16.h>
#include <math.h>

#define KG 8         // dst nodes per block in kron kernel (one per wave, 512 threads)
#define KTHR 512
#define KCHUNK 128   // edges staged in LDS per kron chunk

typedef __attribute__((ext_vector_type(8))) short bfrag;   // 8 bf16 (4 VGPRs)
typedef __attribute__((ext_vector_type(4))) float cfrag;   // 4 fp32 acc
typedef _Float16 __attribute__((ext_vector_type(2))) half2v;

__device__ __forceinline__ ushort f2bf(float f) {
    __hip_bfloat16 h = __float2bfloat16(f);
    return *(ushort*)&h;
}
__device__ __forceinline__ float bf2f(ushort u) {
    __hip_bfloat16 h;
    *(ushort*)&h = u;
    return __bfloat162float(h);
}
__device__ __forceinline__ uint packf16(float lo, float hi) {
    _Float16 l = (_Float16)lo, h = (_Float16)hi;
    ushort ul = *(ushort*)&l, uh = *(ushort*)&h;
    return (uint)ul | ((uint)uh << 16);
}

// ---------------------------------------------------------------- helpers
__device__ __forceinline__ void blockSum2(float& s1, float& s2, float* red) {
    #pragma unroll
    for (int off = 32; off > 0; off >>= 1) {
        s1 += __shfl_xor(s1, off);
        s2 += __shfl_xor(s2, off);
    }
    int lane = threadIdx.x & 63, wid = threadIdx.x >> 6;
    if (lane == 0) { red[wid] = s1; red[4 + wid] = s2; }
    __syncthreads();
    s1 = red[0] + red[1] + red[2] + red[3];
    s2 = red[4] + red[5] + red[6] + red[7];
}

// VALU-only full-wave sum: DPP row_shr 1/2/4/8 + row_bcast15/31, result via readlane(63).
__device__ __forceinline__ float dppWaveSum(float x) {
    float t;
    t = __int_as_float(__builtin_amdgcn_update_dpp(0, __float_as_int(x), 0x111, 0xf, 0xf, true)); x += t;
    t = __int_as_float(__builtin_amdgcn_update_dpp(0, __float_as_int(x), 0x112, 0xf, 0xf, true)); x += t;
    t = __int_as_float(__builtin_amdgcn_update_dpp(0, __float_as_int(x), 0x114, 0xf, 0xf, true)); x += t;
    t = __int_as_float(__builtin_amdgcn_update_dpp(0, __float_as_int(x), 0x118, 0xf, 0xf, true)); x += t;
    t = __int_as_float(__builtin_amdgcn_update_dpp(0, __float_as_int(x), 0x142, 0xf, 0xf, true)); x += t;
    t = __int_as_float(__builtin_amdgcn_update_dpp(0, __float_as_int(x), 0x143, 0xf, 0xf, true)); x += t;
    return __int_as_float(__builtin_amdgcn_readlane(__float_as_int(x), 63));
}

__device__ __forceinline__ float sigmoidf(float x) { return 1.0f / (1.0f + expf(-x)); }

// ---------------------------------------------------------------- bf16 cast
__global__ __launch_bounds__(256) void cast_bf16_kernel(
    const float* __restrict__ x, ushort* __restrict__ y, int n)
{
    int i = (blockIdx.x * 256 + threadIdx.x) * 4;
    if (i < n) {
        float4 v = *(const float4*)(x + i);
        ushort4 o;
        o.x = f2bf(v.x); o.y = f2bf(v.y); o.z = f2bf(v.z); o.w = f2bf(v.w);
        *(ushort4*)(y + i) = o;
    }
}

// ---------------------------------------------------------------- weight prep (bf16 B^T layouts + f16-packed Wk)
__global__ __launch_bounds__(256) void prep_w_kernel(
    const float* __restrict__ Wn, const float* __restrict__ Wih,
    const float* __restrict__ Whh, const float* __restrict__ Wc,
    const float* __restrict__ b_ih, const float* __restrict__ b_hh,
    const float* __restrict__ Wp, const float* __restrict__ bp,
    const float* __restrict__ Wk,
    ushort* __restrict__ BTn, ushort* __restrict__ BTrz,
    ushort* __restrict__ BTin, ushort* __restrict__ BThn,
    ushort* __restrict__ BTc, float* __restrict__ bias_rz,
    ushort* __restrict__ BTp, float* __restrict__ bp_pad,
    uint* __restrict__ Wkp)
{
    int id = blockIdx.x * 256 + threadIdx.x;
    if (id < 262144) {
        int n = id >> 9, k = id & 511;
        float v = (k < 256) ? Wih[n * 256 + k] : Whh[n * 256 + k - 256];
        BTrz[id] = f2bf(v);
    } else if (id < 327680) {
        int j = id - 262144; int n = j >> 8, k = j & 255;
        BTin[j] = f2bf(Wih[(512 + n) * 256 + k]);
    } else if (id < 393216) {
        int j = id - 327680; int n = j >> 8, k = j & 255;
        BThn[j] = f2bf(Whh[(512 + n) * 256 + k]);
    } else if (id < 458752) {
        int j = id - 393216; int n = j >> 8, k = j & 255;
        BTn[j] = f2bf(Wn[k * 256 + n]);
    } else if (id < 589824) {
        int j = id - 458752; int n = j >> 9, k = j & 511;
        BTc[j] = f2bf(Wc[k * 256 + n]);
    } else if (id < 590336) {
        int n = id - 589824;
        bias_rz[n] = b_ih[n] + b_hh[n];
    } else if (id < 623104) {
        int j = id - 590336; int n = j >> 8, k = j & 255;
        BTp[j] = f2bf((n < 20) ? Wp[k * 20 + n] : 0.f);
    } else if (id < 623232) {
        int n = id - 623104;
        bp_pad[n] = (n < 20) ? bp[n] : 0.f;
    } else if (id < 674432) {
        // Wkp[(a*10+kk)*256 + o] = packf16(Wk[(a*20+2kk)][o], Wk[(a*20+2kk+1)][o])
        int j = id - 623232;
        int row = j >> 8, o = j & 255;
        int a = row / 10, kk = row - a * 10;
        float lo = Wk[(size_t)(a * 20 + 2 * kk) * 256 + o];
        float hi = Wk[(size_t)(a * 20 + 2 * kk + 1) * 256 + o];
        Wkp[j] = packf16(lo, hi);
    }
}

// ---------------------------------------------------------------- generic bf16 MFMA GEMM (128x128, BK=64)
__global__ __launch_bounds__(256) void mfma_gemm_kernel(
    const ushort* __restrict__ A1, const ushort* __restrict__ A2, int ksplit, int lda,
    const ushort* __restrict__ B, const float* __restrict__ bias,
    void* __restrict__ Cout, int store_bf16,
    int M, int N, int K, int ldc)
{
    __shared__ ushort As[128 * 64];
    __shared__ ushort Bs[128 * 64];
    int t = threadIdx.x;
    int m0 = blockIdx.x * 128, n0 = blockIdx.y * 128;
    int w = t >> 6, lane = t & 63;
    int q = lane >> 4, r = lane & 15;
    int wm = (w & 1) * 64, wn = (w >> 1) * 64;

    cfrag acc[4][4] = {};

    int srow_base = t >> 3;
    int skc = t & 7;

    for (int k0 = 0; k0 < K; k0 += 64) {
        const ushort* Ap; int kb;
        if (k0 < ksplit) { Ap = A1; kb = k0; } else { Ap = A2; kb = k0 - ksplit; }
        int4 av[4], bv[4];
        #pragma unroll
        for (int i = 0; i < 4; ++i) {
            int row = i * 32 + srow_base;
            int grow = m0 + row;
            av[i] = make_int4(0, 0, 0, 0);
            if (grow < M) av[i] = *(const int4*)(Ap + (size_t)grow * lda + kb + skc * 8);
            bv[i] = *(const int4*)(B + (size_t)(n0 + row) * K + k0 + skc * 8);
        }
        __syncthreads();
        #pragma unroll
        for (int i = 0; i < 4; ++i) {
            int row = i * 32 + srow_base;
            int off = row * 64 + ((skc ^ (row & 7)) * 8);
            *(int4*)&As[off] = av[i];
            *(int4*)&Bs[off] = bv[i];
        }
        __syncthreads();
        #pragma unroll
        for (int s = 0; s < 2; ++s) {
            bfrag af[4], bfr[4];
            int kc = s * 4 + q;
            #pragma unroll
            for (int mi = 0; mi < 4; ++mi) {
                int arow = wm + mi * 16 + r;
                af[mi] = *(const bfrag*)&As[arow * 64 + ((kc ^ (arow & 7)) * 8)];
            }
            #pragma unroll
            for (int ni = 0; ni < 4; ++ni) {
                int brow = wn + ni * 16 + r;
                bfr[ni] = *(const bfrag*)&Bs[brow * 64 + ((kc ^ (brow & 7)) * 8)];
            }
            #pragma unroll
            for (int mi = 0; mi < 4; ++mi)
                #pragma unroll
                for (int ni = 0; ni < 4; ++ni)
                    acc[mi][ni] = __builtin_amdgcn_mfma_f32_16x16x32_bf16(
                        af[mi], bfr[ni], acc[mi][ni], 0, 0, 0);
        }
    }

    float bvld[4];
    #pragma unroll
    for (int ni = 0; ni < 4; ++ni) bvld[ni] = bias[n0 + wn + ni * 16 + r];
    #pragma unroll
    for (int mi = 0; mi < 4; ++mi) {
        #pragma unroll
        for (int v = 0; v < 4; ++v) {
            int grow = m0 + wm + mi * 16 + q * 4 + v;
            if (grow >= M) continue;
            #pragma unroll
            for (int ni = 0; ni < 4; ++ni) {
                int gcol = n0 + wn + ni * 16 + r;
                if (gcol >= N) continue;
                float val = acc[mi][ni][v] + bvld[ni];
                if (store_bf16) ((ushort*)Cout)[(size_t)grow * ldc + gcol] = f2bf(val);
                else            ((float*)Cout)[(size_t)grow * ldc + gcol] = val;
            }
        }
    }
}

// ---------------------------------------------------------------- LN(20)+relu on npj32 [V,32] -> npj [V,20]
__global__ __launch_bounds__(256) void ln20_kernel(
    const float* __restrict__ npj32, const float* __restrict__ gp,
    const float* __restrict__ betap, float* __restrict__ npj, int V)
{
    int wid = threadIdx.x >> 6, j = threadIdx.x & 63;
    int v = blockIdx.x * 4 + wid;
    if (v >= V) return;
    float acc = (j < 20) ? npj32[(size_t)v * 32 + j] : 0.f;
    float s1 = acc, s2 = acc * acc;
    #pragma unroll
    for (int off = 32; off > 0; off >>= 1) {
        s1 += __shfl_xor(s1, off);
        s2 += __shfl_xor(s2, off);
    }
    float mu = s1 * (1.0f / 20.0f);
    float var = s2 * (1.0f / 20.0f) - mu * mu;
    if (j < 20) {
        float y = (acc - mu) * rsqrtf(var + 1e-5f) * gp[j] + betap[j];
        npj[(size_t)v * 20 + j] = fmaxf(y, 0.f);
    }
}

// ---------------------------------------------------------------- CSR build
__global__ __launch_bounds__(256) void deg_kernel(const int* __restrict__ dst, int* __restrict__ deg, int E) {
    int e = blockIdx.x * 256 + threadIdx.x;
    if (e < E) atomicAdd(&deg[dst[e]], 1);
}

__global__ __launch_bounds__(1024) void scan_kernel(const int* __restrict__ deg, int* __restrict__ row, int V) {
    __shared__ int wsum[16];
    __shared__ int carry_sh;
    int t = threadIdx.x, lane = t & 63, wid = t >> 6;
    if (t == 0) carry_sh = 0;
    __syncthreads();
    for (int base = 0; base < V; base += 1024) {
        int i = base + t;
        int val = (i < V) ? deg[i] : 0;
        #pragma unroll
        for (int s = 1; s < 64; s <<= 1) {
            int n = __shfl_up(val, s);
            if (lane >= s) val += n;
        }
        if (lane == 63) wsum[wid] = val;
        __syncthreads();
        if (wid == 0) {
            int x = (lane < 16) ? wsum[lane] : 0;
            #pragma unroll
            for (int s = 1; s < 16; s <<= 1) {
                int n = __shfl_up(x, s);
                if (lane >= s) x += n;
            }
            if (lane < 16) wsum[lane] = x;
        }
        __syncthreads();
        int wprefix = (wid > 0) ? wsum[wid - 1] : 0;
        int c = carry_sh;
        int incl = c + wprefix + val;
        if (i < V) row[i + 1] = incl;
        __syncthreads();
        if (t == 1023) carry_sh = incl;
    }
    if (t == 0) row[0] = 0;
}

__global__ __launch_bounds__(256) void scatter_kernel(
    const int* __restrict__ dst, const int* __restrict__ row,
    int* __restrict__ cnt, int* __restrict__ eorder, int E)
{
    int e = blockIdx.x * 256 + threadIdx.x;
    if (e < E) {
        int d = dst[e];
        int pos = row[d] + atomicAdd(&cnt[d], 1);
        eorder[pos] = e;
    }
}

// ---------------------------------------------------------------- per-node edge-logit projections
__global__ __launch_bounds__(256) void nodeproj_kernel(
    const float* __restrict__ nf, const float* __restrict__ We,
    float* __restrict__ pd, float* __restrict__ ps, int V)
{
    int wid = threadIdx.x >> 6, lane = threadIdx.x & 63;
    int v = blockIdx.x * 4 + wid;
    if (v >= V) return;
    const float* row = nf + (size_t)v * 256;
    int i = lane * 4;
    float4 x  = *(const float4*)(row + i);
    float4 wd = *(const float4*)(We + i);
    float4 wsv = *(const float4*)(We + 256 + i);
    float sd = x.x * wd.x + x.y * wd.y + x.z * wd.z + x.w * wd.w;
    float ss = x.x * wsv.x + x.y * wsv.y + x.z * wsv.z + x.w * wsv.w;
    #pragma unroll
    for (int off = 32; off > 0; off >>= 1) {
        sd += __shfl_xor(sd, off);
        ss += __shfl_xor(ss, off);
    }
    if (lane == 0) { pd[v] = sd; ps[v] = ss; }
}

// ---------------------------------------------------------------- edge prep (eorder order)
__global__ __launch_bounds__(256) void edgeprep_kernel(
    const int* __restrict__ eorder, const int* __restrict__ src, const int* __restrict__ dst,
    const float* __restrict__ pd, const float* __restrict__ ps, const float* __restrict__ be,
    float* __restrict__ logitOrd, int* __restrict__ srcOrd, int E)
{
    int p = blockIdx.x * 256 + threadIdx.x;
    if (p < E) {
        int e = eorder[p];
        int s = src[e], d = dst[e];
        srcOrd[p] = s;
        logitOrd[p] = fmaxf(pd[d] + ps[s] + be[0], 0.f);
    }
}

// ---------------------------------------------------------------- kron branch (fused, KG=8, f16 dot2 in BOTH stages)
// Stage 1: 512 threads, h-split over a-pairs; T stored a-pair-packed f16: T16[g][kk][c] with
// lo=T[2kk][c], hi=T[2kk+1][c].  Stage 2: one wave per dst; per edge 40 v_dot2_f32_f16
// (vs 80 f32 FMA), 4-edge unroll interleaves 8 independent DPP reduction chains.
__global__ __launch_bounds__(KTHR) void kron_kernel(
    const float* __restrict__ npj, const int* __restrict__ srcOrd,
    const int* __restrict__ rowPtr,
    const uint* __restrict__ Wkp, const float* __restrict__ bk,
    const float* __restrict__ gkv, const float* __restrict__ betak,
    ushort* __restrict__ acat, int V)
{
    __shared__ uint T16[KG * 10 * 256];    // 80 KB, a-pair-packed f16
    __shared__ uint dshp[KG * 10];         // f16-packed d
    __shared__ uint sEp[KCHUNK * 12];      // 6 KB, rows padded 10->12 for b128 alignment
    int t = threadIdx.x;
    int v0 = blockIdx.x * KG;

    if (t < KG * 10) {
        int g = t / 10, kk = t - g * 10;
        int v = v0 + g;
        float lo = 0.f, hi = 0.f;
        if (v < V) {
            lo = npj[(size_t)v * 20 + 2 * kk];
            hi = npj[(size_t)v * 20 + 2 * kk + 1];
        }
        dshp[t] = packf16(lo, hi);
    }
    __syncthreads();

    // ---- stage 1 (packed-pair output)
    {
        uint dreg[KG][10];
        #pragma unroll
        for (int g = 0; g < KG; ++g)
            #pragma unroll
            for (int kk = 0; kk < 10; ++kk) dreg[g][kk] = dshp[g * 10 + kk];

        int c = t & 255, h = t >> 8;   // h in {0,1}
        int kk0 = h * 5;
        for (int kk = kk0; kk < kk0 + 5; ++kk) {
            uint wv0[10], wv1[10];
            #pragma unroll
            for (int j = 0; j < 10; ++j)
                wv0[j] = Wkp[(size_t)((2 * kk) * 10 + j) * 256 + c];
            #pragma unroll
            for (int j = 0; j < 10; ++j)
                wv1[j] = Wkp[(size_t)((2 * kk + 1) * 10 + j) * 256 + c];
            #pragma unroll
            for (int g = 0; g < KG; ++g) {
                float s0 = 0.f, s1 = 0.f;
                #pragma unroll
                for (int j = 0; j < 10; ++j) {
                    half2v d2 = *(half2v*)&dreg[g][j];
                    s0 = __builtin_amdgcn_fdot2(d2, *(half2v*)&wv0[j], s0, false);
                    s1 = __builtin_amdgcn_fdot2(d2, *(half2v*)&wv1[j], s1, false);
                }
                T16[(g * 10 + kk) * 256 + c] = packf16(s0, s1);
            }
        }
    }
    __syncthreads();

    // ---- stage 2
    int wid = t >> 6, lane = t & 63;
    int v = v0 + wid;
    int c0 = lane * 4;

    uint Tp[10][4];
    if (v < V) {
        #pragma unroll
        for (int kk = 0; kk < 10; ++kk) {
            int4 tv = *(const int4*)&T16[(wid * 10 + kk) * 256 + c0];
            Tp[kk][0] = (uint)tv.x; Tp[kk][1] = (uint)tv.y;
            Tp[kk][2] = (uint)tv.z; Tp[kk][3] = (uint)tv.w;
        }
    } else {
        #pragma unroll
        for (int kk = 0; kk < 10; ++kk) {
            Tp[kk][0] = 0u; Tp[kk][1] = 0u; Tp[kk][2] = 0u; Tp[kk][3] = 0u;
        }
    }
    float4 bkv = *(const float4*)(bk + c0);
    float4 gk4 = *(const float4*)(gkv + c0);
    float4 bt4 = *(const float4*)(betak + c0);

    int eBase = rowPtr[v0];
    int vEnd = (v0 + KG < V) ? (v0 + KG) : V;
    int eEndB = rowPtr[vEnd];
    int myE0 = (v < V) ? rowPtr[v] : 0;
    int myE1 = (v < V) ? rowPtr[v + 1] : 0;

    float a0 = 0.f, a1 = 0.f, a2 = 0.f, a3 = 0.f;

    for (int base = eBase; base < eEndB; base += KCHUNK) {
        int nC = eEndB - base; if (nC > KCHUNK) nC = KCHUNK;
        __syncthreads();   // previous chunk fully consumed (covers stage-1 on first iter)
        for (int idx = t; idx < nC * 10; idx += KTHR) {
            int le = idx / 10, kk = idx - le * 10;
            float2 v2 = *(const float2*)(npj + (size_t)srcOrd[base + le] * 20 + 2 * kk);
            sEp[le * 12 + kk] = packf16(v2.x, v2.y);
        }
        __syncthreads();

        int lo = (myE0 > base) ? myE0 : base;
        int hi = (myE1 < base + nC) ? myE1 : base + nC;
        int p = lo;
        for (; p + 3 < hi; p += 4) {
            float ya[4][4];
            #pragma unroll
            for (int e = 0; e < 4; ++e) {
                const uint* sp = &sEp[(p + e - base) * 12];
                int4 w0 = *(const int4*)(sp);
                int4 w1 = *(const int4*)(sp + 4);
                int2 w2 = *(const int2*)(sp + 8);
                uint sv[10] = {(uint)w0.x, (uint)w0.y, (uint)w0.z, (uint)w0.w,
                               (uint)w1.x, (uint)w1.y, (uint)w1.z, (uint)w1.w,
                               (uint)w2.x, (uint)w2.y};
                ya[e][0] = bkv.x; ya[e][1] = bkv.y; ya[e][2] = bkv.z; ya[e][3] = bkv.w;
                #pragma unroll
                for (int kk = 0; kk < 10; ++kk) {
                    half2v s2h = *(half2v*)&sv[kk];
                    ya[e][0] = __builtin_amdgcn_fdot2(s2h, *(half2v*)&Tp[kk][0], ya[e][0], false);
                    ya[e][1] = __builtin_amdgcn_fdot2(s2h, *(half2v*)&Tp[kk][1], ya[e][1], false);
                    ya[e][2] = __builtin_amdgcn_fdot2(s2h, *(half2v*)&Tp[kk][2], ya[e][2], false);
                    ya[e][3] = __builtin_amdgcn_fdot2(s2h, *(half2v*)&Tp[kk][3], ya[e][3], false);
                }
            }
            float pre1[4], pre2[4];
            #pragma unroll
            for (int e = 0; e < 4; ++e) {
                pre1[e] = ya[e][0] + ya[e][1] + ya[e][2] + ya[e][3];
                pre2[e] = ya[e][0] * ya[e][0] + ya[e][1] * ya[e][1]
                        + ya[e][2] * ya[e][2] + ya[e][3] * ya[e][3];
            }
            float s1v[4], s2v[4];
            #pragma unroll
            for (int e = 0; e < 4; ++e) {
                s1v[e] = dppWaveSum(pre1[e]);
                s2v[e] = dppWaveSum(pre2[e]);
            }
            #pragma unroll
            for (int e = 0; e < 4; ++e) {
                float mu = s1v[e] * (1.0f / 256.0f);
                float rs = rsqrtf(s2v[e] * (1.0f / 256.0f) - mu * mu + 1e-5f);
                a0 += fmaxf((ya[e][0] - mu) * rs * gk4.x + bt4.x, 0.f);
                a1 += fmaxf((ya[e][1] - mu) * rs * gk4.y + bt4.y, 0.f);
                a2 += fmaxf((ya[e][2] - mu) * rs * gk4.z + bt4.z, 0.f);
                a3 += fmaxf((ya[e][3] - mu) * rs * gk4.w + bt4.w, 0.f);
            }
        }
        for (; p < hi; ++p) {
            const uint* sp = &sEp[(p - base) * 12];
            int4 w0 = *(const int4*)(sp);
            int4 w1 = *(const int4*)(sp + 4);
            int2 w2 = *(const int2*)(sp + 8);
            uint sv[10] = {(uint)w0.x, (uint)w0.y, (uint)w0.z, (uint)w0.w,
                           (uint)w1.x, (uint)w1.y, (uint)w1.z, (uint)w1.w,
                           (uint)w2.x, (uint)w2.y};
            float y0 = bkv.x, y1 = bkv.y, y2 = bkv.z, y3 = bkv.w;
            #pragma unroll
            for (int kk = 0; kk < 10; ++kk) {
                half2v s2h = *(half2v*)&sv[kk];
                y0 = __builtin_amdgcn_fdot2(s2h, *(half2v*)&Tp[kk][0], y0, false);
                y1 = __builtin_amdgcn_fdot2(s2h, *(half2v*)&Tp[kk][1], y1, false);
                y2 = __builtin_amdgcn_fdot2(s2h, *(half2v*)&Tp[kk][2], y2, false);
                y3 = __builtin_amdgcn_fdot2(s2h, *(half2v*)&Tp[kk][3], y3, false);
            }
            float s1 = dppWaveSum(y0 + y1 + y2 + y3);
            float s2 = dppWaveSum(y0 * y0 + y1 * y1 + y2 * y2 + y3 * y3);
            float mu = s1 * (1.0f / 256.0f);
            float rs = rsqrtf(s2 * (1.0f / 256.0f) - mu * mu + 1e-5f);
            a0 += fmaxf((y0 - mu) * rs * gk4.x + bt4.x, 0.f);
            a1 += fmaxf((y1 - mu) * rs * gk4.y + bt4.y, 0.f);
            a2 += fmaxf((y2 - mu) * rs * gk4.z + bt4.z, 0.f);
            a3 += fmaxf((y3 - mu) * rs * gk4.w + bt4.w, 0.f);
        }
    }
    if (v < V) {
        ushort4 o;
        o.x = f2bf(a0); o.y = f2bf(a1); o.z = f2bf(a2); o.w = f2bf(a3);
        *(ushort4*)(acat + (size_t)v * 512 + 256 + c0) = o;
    }
}

// ---------------------------------------------------------------- attention stats per dst (linear reads)
__global__ __launch_bounds__(256) void att_kernel(
    const float* __restrict__ logitOrd, const int* __restrict__ rowPtr,
    float* __restrict__ mArr, float* __restrict__ invArr, int V)
{
    int wid = threadIdx.x >> 6, lane = threadIdx.x & 63;
    int v = blockIdx.x * 4 + wid;
    if (v >= V) return;
    int e0 = rowPtr[v], e1 = rowPtr[v + 1];
    float m = -1e30f;
    for (int p = e0 + lane; p < e1; p += 64) m = fmaxf(m, logitOrd[p]);
    #pragma unroll
    for (int off = 32; off > 0; off >>= 1) m = fmaxf(m, __shfl_xor(m, off));
    float d = 0.f;
    for (int p = e0 + lane; p < e1; p += 64) d += expf(logitOrd[p] - m);
    #pragma unroll
    for (int off = 32; off > 0; off >>= 1) d += __shfl_xor(d, off);
    if (lane == 0) {
        mArr[v] = m;
        invArr[v] = (e1 > e0) ? (1.0f / d) : 0.f;
    }
}

// ---------------------------------------------------------------- weighted context (bf16 hv, unroll x4)
__global__ __launch_bounds__(256) void ctx_kernel(
    const ushort* __restrict__ hv_bf, const float* __restrict__ logitOrd,
    const float* __restrict__ mArr, const float* __restrict__ invArr,
    const int* __restrict__ srcOrd, const int* __restrict__ rowPtr,
    ushort* __restrict__ ctx_bf, int V)
{
    int v = blockIdx.x;
    int t = threadIdx.x;
    int e0 = rowPtr[v], e1 = rowPtr[v + 1];
    float m = mArr[v], inv = invArr[v];
    float acc = 0.f;
    int p = e0;
    for (; p + 3 < e1; p += 4) {
        int s0 = srcOrd[p], s1 = srcOrd[p + 1], s2 = srcOrd[p + 2], s3 = srcOrd[p + 3];
        float w0 = expf(logitOrd[p] - m) * inv;
        float w1 = expf(logitOrd[p + 1] - m) * inv;
        float w2 = expf(logitOrd[p + 2] - m) * inv;
        float w3 = expf(logitOrd[p + 3] - m) * inv;
        float h0 = bf2f(hv_bf[(size_t)s0 * 256 + t]);
        float h1 = bf2f(hv_bf[(size_t)s1 * 256 + t]);
        float h2 = bf2f(hv_bf[(size_t)s2 * 256 + t]);
        float h3 = bf2f(hv_bf[(size_t)s3 * 256 + t]);
        acc += w0 * h0 + w1 * h1 + w2 * h2 + w3 * h3;
    }
    for (; p < e1; ++p) {
        float wgt = expf(logitOrd[p] - m) * inv;
        acc += wgt * bf2f(hv_bf[(size_t)srcOrd[p] * 256 + t]);
    }
    ctx_bf[(size_t)v * 256 + t] = f2bf(fmaxf(acc, 0.f));
}

// ---------------------------------------------------------------- GRU gates + LN -> bf16 into acat[:,0:256]
__global__ __launch_bounds__(256) void gru_ln_kernel(
    const ushort* __restrict__ rz, const ushort* __restrict__ inb,
    const ushort* __restrict__ hnb, const float* __restrict__ nf,
    const float* __restrict__ g_ln, const float* __restrict__ b_ln,
    ushort* __restrict__ acat, int V)
{
    __shared__ float red[8];
    int v = blockIdx.x, t = threadIdx.x;
    float r = sigmoidf(bf2f(rz[(size_t)v * 512 + t]));
    float z = sigmoidf(bf2f(rz[(size_t)v * 512 + 256 + t]));
    float n = tanhf(bf2f(inb[(size_t)v * 256 + t]) + r * bf2f(hnb[(size_t)v * 256 + t]));
    float h = (1.f - z) * n + z * nf[(size_t)v * 256 + t];
    float x = fmaxf(h, 0.f);
    float s1 = x, s2 = x * x;
    blockSum2(s1, s2, red);
    float mu = s1 * (1.0f / 256.0f);
    float var = s2 * (1.0f / 256.0f) - mu * mu;
    float y = (x - mu) * rsqrtf(var + 1e-5f) * g_ln[t] + b_ln[t];
    acat[(size_t)v * 512 + t] = f2bf(y);
}

// ---------------------------------------------------------------- row LayerNorm (optional relu)
__global__ __launch_bounds__(256) void ln_kernel(
    const float* __restrict__ in, float* __restrict__ out,
    const float* __restrict__ g, const float* __restrict__ b, int relu_after)
{
    __shared__ float red[8];
    int v = blockIdx.x, t = threadIdx.x;
    float x = in[(size_t)v * 256 + t];
    float s1 = x, s2 = x * x;
    blockSum2(s1, s2, red);
    float mu = s1 * (1.0f / 256.0f);
    float var = s2 * (1.0f / 256.0f) - mu * mu;
    float y = (x - mu) * rsqrtf(var + 1e-5f) * g[t] + b[t];
    if (relu_after) y = fmaxf(y, 0.f);
    out[(size_t)v * 256 + t] = y;
}

// ---------------------------------------------------------------- launcher
extern "C" void kernel_launch(void* const* d_in, const int* in_sizes, int n_in,
                              void* d_out, int out_size, void* d_ws, size_t ws_size,
                              hipStream_t stream)
{
    const float* nf    = (const float*)d_in[0];
    const int*   src   = (const int*)d_in[1];
    const int*   dst   = (const int*)d_in[2];
    const float* Wp    = (const float*)d_in[3];
    const float* bp    = (const float*)d_in[4];
    const float* gp    = (const float*)d_in[5];
    const float* betap = (const float*)d_in[6];
    const float* Wk    = (const float*)d_in[7];
    const float* bk    = (const float*)d_in[8];
    const float* gk    = (const float*)d_in[9];
    const float* betak = (const float*)d_in[10];
    const float* We    = (const float*)d_in[11];
    const float* be    = (const float*)d_in[12];
    const float* Wn    = (const float*)d_in[13];
    const float* bn    = (const float*)d_in[14];
    const float* W_ih  = (const float*)d_in[15];
    const float* W_hh  = (const float*)d_in[16];
    const float* b_ih  = (const float*)d_in[17];
    const float* b_hh  = (const float*)d_in[18];
    const float* g_ln  = (const float*)d_in[19];
    const float* bt_ln = (const float*)d_in[20];
    const float* Wc    = (const float*)d_in[21];
    const float* bc    = (const float*)d_in[22];
    const float* gc    = (const float*)d_in[23];
    const float* betac = (const float*)d_in[24];

    int V = in_sizes[0] / 256;
    int E = in_sizes[1];

    char* w = (char*)d_ws;
    auto alloc = [&](size_t bytes) -> char* {
        char* p = w;
        w += (bytes + 255) & ~(size_t)255;
        return p;
    };
    float*  npj      = (float*)alloc((size_t)V * 20 * 4);
    float*  npj32    = (float*)alloc((size_t)V * 32 * 4);
    ushort* acat     = (ushort*)alloc((size_t)V * 512 * 2);
    ushort* nf_bf    = (ushort*)alloc((size_t)V * 256 * 2);
    ushort* ctx_bf   = (ushort*)alloc((size_t)V * 256 * 2);
    ushort* rz_bf    = (ushort*)alloc((size_t)V * 512 * 2);
    ushort* hv_bf    = rz_bf;  // alias: hv dead before rz GEMM writes
    ushort* in_bf    = (ushort*)alloc((size_t)V * 256 * 2);
    ushort* hn_bf    = (ushort*)alloc((size_t)V * 256 * 2);
    ushort* BTn      = (ushort*)alloc(65536 * 2);
    ushort* BTrz     = (ushort*)alloc(262144 * 2);
    ushort* BTin     = (ushort*)alloc(65536 * 2);
    ushort* BThn     = (ushort*)alloc(65536 * 2);
    ushort* BTc      = (ushort*)alloc(131072 * 2);
    ushort* BTp      = (ushort*)alloc(32768 * 2);
    float*  bias_rz  = (float*)alloc(512 * 4);
    float*  bp_pad   = (float*)alloc(128 * 4);
    float*  logitOrd = (float*)alloc((size_t)E * 4);
    int*    srcOrd   = (int*)alloc((size_t)E * 4);
    float*  pd       = (float*)alloc((size_t)V * 4);
    float*  ps       = (float*)alloc((size_t)V * 4);
    float*  mArr     = (float*)alloc((size_t)V * 4);
    float*  invArr   = (float*)alloc((size_t)V * 4);
    int*    deg      = (int*)alloc((size_t)V * 4);
    int*    cnt      = (int*)alloc((size_t)V * 4);
    int*    rowp     = (int*)alloc((size_t)(V + 1) * 4);
    int*    eorder   = (int*)alloc((size_t)E * 4);
    uint*   Wkp      = (uint*)alloc((size_t)51200 * 4);   // f16-packed Wk [200][256]

    hipMemsetAsync(deg, 0, (size_t)V * 4, stream);
    hipMemsetAsync(cnt, 0, (size_t)V * 4, stream);

    int mt = (V + 127) / 128;

    cast_bf16_kernel<<<(V * 64 + 255) / 256, 256, 0, stream>>>(nf, nf_bf, V * 256);
    prep_w_kernel<<<(674432 + 255) / 256, 256, 0, stream>>>(
        Wn, W_ih, W_hh, Wc, b_ih, b_hh, Wp, bp, Wk,
        BTn, BTrz, BTin, BThn, BTc, bias_rz, BTp, bp_pad, Wkp);

    // npj32 = nf @ Wp + bp (N padded to 32, via 128-wide tile w/ zero rows)
    mfma_gemm_kernel<<<dim3(mt, 1), 256, 0, stream>>>(
        nf_bf, nf_bf, 256, 256, BTp, bp_pad, npj32, 0, V, 32, 256, 32);
    ln20_kernel<<<(V + 3) / 4, 256, 0, stream>>>(npj32, gp, betap, npj, V);

    deg_kernel<<<(E + 255) / 256, 256, 0, stream>>>(dst, deg, E);
    scan_kernel<<<1, 1024, 0, stream>>>(deg, rowp, V);
    scatter_kernel<<<(E + 255) / 256, 256, 0, stream>>>(dst, rowp, cnt, eorder, E);
    nodeproj_kernel<<<(V + 3) / 4, 256, 0, stream>>>(nf, We, pd, ps, V);
    edgeprep_kernel<<<(E + 255) / 256, 256, 0, stream>>>(
        eorder, src, dst, pd, ps, be, logitOrd, srcOrd, E);

    // hv = nf @ Wn + bn  -> bf16 (aliased on rz_bf; consumed by ctx before rz GEMM)
    mfma_gemm_kernel<<<dim3(mt, 2), 256, 0, stream>>>(
        nf_bf, nf_bf, 256, 256, BTn, bn, hv_bf, 1, V, 256, 256, 256);
    att_kernel<<<(V + 3) / 4, 256, 0, stream>>>(logitOrd, rowp, mArr, invArr, V);
    ctx_kernel<<<V, 256, 0, stream>>>(hv_bf, logitOrd, mArr, invArr, srcOrd, rowp, ctx_bf, V);

    kron_kernel<<<(V + KG - 1) / KG, KTHR, 0, stream>>>(
        npj, srcOrd, rowp, Wkp, bk, gk, betak, acat, V);

    // rz = [ctx|nf] @ BTrz + (b_ih+b_hh)
    mfma_gemm_kernel<<<dim3(mt, 4), 256, 0, stream>>>(
        ctx_bf, nf_bf, 256, 256, BTrz, bias_rz, rz_bf, 1, V, 512, 512, 512);
    mfma_gemm_kernel<<<dim3(mt, 2), 256, 0, stream>>>(
        ctx_bf, ctx_bf, 256, 256, BTin, b_ih + 512, in_bf, 1, V, 256, 256, 256);
    mfma_gemm_kernel<<<dim3(mt, 2), 256, 0, stream>>>(
        nf_bf, nf_bf, 256, 256, BThn, b_hh + 512, hn_bf, 1, V, 256, 256, 256);

    gru_ln_kernel<<<V, 256, 0, stream>>>(rz_bf, in_bf, hn_bf, nf, g_ln, bt_ln, acat, V);

    mfma_gemm_kernel<<<dim3(mt, 2), 256, 0, stream>>>(
        acat, acat, 512, 512, BTc, bc, (float*)d_out, 0, V, 256, 512, 256);
    ln_kernel<<<V, 256, 0, stream>>>((float*)d_out, (float*)d_out, gc, betac, 1);
}